// Round 15
// baseline (108.686 us; speedup 1.0000x reference)
//
#include <hip/hip_runtime.h>
#include <math.h>

#define BB 8
#define NN 1024
#define MM 128
#define FOUT 64
#define HIDN 128

// ---------------- workspace layout (floats) ----------------
#define OFF_H       0                       // B*N*64 = 524288
#define OFF_HMA     524288                  // B*M*64 = 65536
#define OFF_HA1     589824                  // B*N
#define OFF_HA2     598016                  // B*N
#define OFF_HAM1    606208                  // B*N
#define OFF_HMAAM2  614400                  // B*M
#define OFF_RMASK   615424                  // B*N (ints)
#define OFF_WAM3    623616                  // 16
#define OFF_HPRIME  623632                  // B*N*128 = 1048576
#define OFF_RDIR    1672208                 // B*N*16 u64 = 262144 floats
#define OFF_OPMB    1934352                 // B*N*2 u64 = 32768 floats
#define OFF_WT1HI   1967120                 // 128*128 u16 = 8192 floats
#define OFF_WT1LO   1975312
#define OFF_WT2HI   1983504
#define OFF_WT2LO   1991696
#define OFF_WTOHI   1999888                 // 64*128 u16 = 4096 floats
#define OFF_WTOLO   2003984
#define OFF_HTHI    2008080                 // B*64*1024 u16 = 262144 floats
#define OFF_HTLO    2270224
#define OFF_HMATHI  2532368                 // B*64*128 u16 = 32768 floats
#define OFF_HMATLO  2565136
#define OFF_TRM     2597904                 // B*64*1024 u16 = 262144 floats
// total ~2,860,048 floats ~ 11.4 MB

typedef __attribute__((ext_vector_type(8))) short bf16x8;
typedef __attribute__((ext_vector_type(8))) unsigned short u16x8;
typedef __attribute__((ext_vector_type(4))) float f32x4;

__device__ __forceinline__ void splitbf(float v, unsigned short& h, unsigned short& l) {
    unsigned u = __float_as_uint(v);
    unsigned hb = (u + 0x7FFFu + ((u >> 16) & 1u)) >> 16;
    float hf = __uint_as_float(hb << 16);
    float lf = v - hf;
    unsigned ul = __float_as_uint(lf);
    unsigned lb = (ul + 0x7FFFu + ((ul >> 16) & 1u)) >> 16;
    h = (unsigned short)hb; l = (unsigned short)lb;
}

__device__ __forceinline__ unsigned short tobf(float v) {
    unsigned u = __float_as_uint(v);
    return (unsigned short)((u + 0x7FFFu + ((u >> 16) & 1u)) >> 16);
}

// ================= Kernel 1 (fused) =========================================
__global__ __launch_bounds__(256) void k1_prep(
    const float* __restrict__ x, const float* __restrict__ y,
    const int* __restrict__ op_ma_adj,
    const int* __restrict__ op_adj, const int* __restrict__ ma_adj,
    const float* __restrict__ w_op, const float* __restrict__ w_ma,
    const float* __restrict__ w_edge,
    const float* __restrict__ att_op, const float* __restrict__ att_ma,
    const float* __restrict__ w1_g, const float* __restrict__ w2_g,
    const float* __restrict__ wo_g,
    float* __restrict__ h, float* __restrict__ h_ma,
    float* __restrict__ ha1, float* __restrict__ ha2, float* __restrict__ ham1,
    float* __restrict__ hmaam2, int* __restrict__ rmask, float* __restrict__ wam3,
    unsigned long long* __restrict__ rowdir, unsigned long long* __restrict__ opmb,
    unsigned short* __restrict__ trm,
    unsigned short* __restrict__ wt1hi, unsigned short* __restrict__ wt1lo,
    unsigned short* __restrict__ wt2hi, unsigned short* __restrict__ wt2lo,
    unsigned short* __restrict__ wtohi, unsigned short* __restrict__ wtolo,
    unsigned short* __restrict__ hthi, unsigned short* __restrict__ htlo,
    unsigned short* __restrict__ hmathi, unsigned short* __restrict__ hmatlo)
{
    __shared__ float wlds[64 * 64];          // 16 KB multi-purpose
    __shared__ unsigned hstage[32 * 64];     // 8 KB packed hi|lo<<16
    int bid = blockIdx.x;
    int t = threadIdx.x;
    int lane = t & 63;
    int wv = t >> 6;

    if (bid < 256) {
        // ---- h section: 32 rows per block ----
        int b = bid >> 5;
        int n0g = (bid & 31) * 32;
        for (int k = t; k < 4096; k += 256) wlds[k] = w_op[k];
        float a1c = att_op[lane], a2c = att_op[64 + lane], am1c = att_ma[lane];
        __syncthreads();
        #pragma unroll
        for (int p = 0; p < 8; ++p) {
            int row = b * NN + n0g + p * 4 + wv;
            float xv = x[(size_t)row * 64 + lane];
            float acc = 0.f;
            #pragma unroll
            for (int i = 0; i < 64; ++i) {
                float xi = __shfl(xv, i);
                acc += xi * wlds[i * 64 + lane];
            }
            h[(size_t)row * 64 + lane] = acc;
            unsigned short hs, ls;
            splitbf(acc, hs, ls);
            hstage[(p * 4 + wv) * 64 + lane] = (unsigned)hs | ((unsigned)ls << 16);
            float d1 = acc * a1c, d2 = acc * a2c, d3 = acc * am1c;
            #pragma unroll
            for (int m = 32; m; m >>= 1) {
                d1 += __shfl_xor(d1, m);
                d2 += __shfl_xor(d2, m);
                d3 += __shfl_xor(d3, m);
            }
            int v0 = op_ma_adj[(size_t)row * 128 + lane];
            int v1 = op_ma_adj[(size_t)row * 128 + 64 + lane];
            unsigned long long w0 = __ballot(v0 != 0);
            unsigned long long w1 = __ballot(v1 != 0);
            if (lane == 0) {
                ha1[row] = d1; ha2[row] = d2; ham1[row] = d3;
                opmb[row * 2] = w0; opmb[row * 2 + 1] = w1;
                rmask[row] = ((w0 | w1) == 0ULL) ? 1 : 0;
            }
        }
        __syncthreads();
        {
            int plane = t >> 7;          // 0 hi, 1 lo
            int q = t & 127;
            int o = q >> 1;
            int hf = q & 1;
            int sh = plane * 16;
            unsigned short* dst = plane ? htlo : hthi;
            u16x8 pk0, pk1;
            #pragma unroll
            for (int k = 0; k < 8; ++k)
                pk0[k] = (unsigned short)((hstage[(hf * 16 + k) * 64 + o] >> sh) & 0xFFFFu);
            #pragma unroll
            for (int k = 0; k < 8; ++k)
                pk1[k] = (unsigned short)((hstage[(hf * 16 + 8 + k) * 64 + o] >> sh) & 0xFFFFu);
            size_t base = ((size_t)(b * 64 + o)) * 1024 + n0g + hf * 16;
            *(u16x8*)&dst[base] = pk0;
            *(u16x8*)&dst[base + 8] = pk1;
        }
    } else if (bid < 288) {
        // ---- h_ma section: 32 rows per block ----
        int bb = (bid - 256) >> 2;
        int m0 = ((bid - 256) & 3) * 32;
        for (int k = t; k < 4096; k += 256) wlds[k] = w_ma[k];
        float am2c = att_ma[64 + lane];
        __syncthreads();
        #pragma unroll
        for (int p = 0; p < 8; ++p) {
            int row = bb * MM + m0 + p * 4 + wv;
            float yv = y[(size_t)row * 64 + lane];
            float acc = 0.f;
            #pragma unroll
            for (int i = 0; i < 64; ++i) {
                float yi = __shfl(yv, i);
                acc += yi * wlds[i * 64 + lane];
            }
            h_ma[(size_t)row * 64 + lane] = acc;
            unsigned short hs, ls;
            splitbf(acc, hs, ls);
            hstage[(p * 4 + wv) * 64 + lane] = (unsigned)hs | ((unsigned)ls << 16);
            float d = acc * am2c;
            #pragma unroll
            for (int m = 32; m; m >>= 1) d += __shfl_xor(d, m);
            if (lane == 0) hmaam2[row] = d;
        }
        __syncthreads();
        {
            int plane = t >> 7;
            int q = t & 127;
            int o = q >> 1;
            int hf = q & 1;
            int sh = plane * 16;
            unsigned short* dst = plane ? hmatlo : hmathi;
            u16x8 pk0, pk1;
            #pragma unroll
            for (int k = 0; k < 8; ++k)
                pk0[k] = (unsigned short)((hstage[(hf * 16 + k) * 64 + o] >> sh) & 0xFFFFu);
            #pragma unroll
            for (int k = 0; k < 8; ++k)
                pk1[k] = (unsigned short)((hstage[(hf * 16 + 8 + k) * 64 + o] >> sh) & 0xFFFFu);
            size_t base = ((size_t)(bb * 64 + o)) * 128 + m0 + hf * 16;
            *(u16x8*)&dst[base] = pk0;
            *(u16x8*)&dst[base + 8] = pk1;
        }
    } else if (bid == 288) {
        if (t < 16) {
            float s = 0.f;
            for (int o = 0; o < 64; ++o) s += w_edge[t * 64 + o] * att_ma[128 + o];
            wam3[t] = s;
        }
    } else if (bid < 2337) {
        // ---- adjacency row-pack: 4 rows/block, int4 coalesced one-pass ----
        unsigned char (*nib)[4][64] = (unsigned char(*)[4][64])wlds; // 1 KB
        int p = bid - 289;                   // 0..2047
        int b = p >> 8;
        int rg = p & 255;
        int rl = t >> 6;                     // local row 0..3
        int row = rg * 4 + rl;
        const int4* oprow = (const int4*)(op_adj + ((size_t)(b * NN + row)) * NN);
        const int4* marow = (const int4*)(ma_adj + ((size_t)(b * NN + row)) * NN);
        #pragma unroll
        for (int p2 = 0; p2 < 4; ++p2) {
            int4 vo = oprow[p2 * 64 + lane];
            int4 vm = marow[p2 * 64 + lane];
            unsigned nb = ((vo.x | vm.x) ? 1u : 0u) | ((vo.y | vm.y) ? 2u : 0u)
                        | ((vo.z | vm.z) ? 4u : 0u) | ((vo.w | vm.w) ? 8u : 0u);
            nib[rl][p2][lane] = (unsigned char)nb;
        }
        __syncthreads();
        if (t < 64) {
            int arl = t >> 4, q = t & 15;
            const unsigned* nw = (const unsigned*)&nib[arl][q >> 2][(q & 3) * 16];
            unsigned long long w = 0;
            #pragma unroll
            for (int u = 0; u < 4; ++u) {
                unsigned v = nw[u];
                w |= (unsigned long long)(v & 0xFu)         << (16 * u);
                w |= (unsigned long long)((v >> 8) & 0xFu)  << (16 * u + 4);
                w |= (unsigned long long)((v >> 16) & 0xFu) << (16 * u + 8);
                w |= (unsigned long long)((v >> 24) & 0xFu) << (16 * u + 12);
            }
            int jrow = rg * 4 + arl;
            rowdir[((size_t)(b * NN + jrow)) * 16 + q] = w;
            #pragma unroll
            for (int s = 0; s < 4; ++s) {
                trm[((size_t)(b * 64 + q * 4 + s)) * 1024 + jrow] =
                    (unsigned short)((w >> (16 * s)) & 0xFFFFu);
            }
        }
    } else {
        // ---- MLP weight transpose + bf16 hi/lo split, 32x32 tiles ----
        float (*tls)[33] = (float(*)[33])wlds;
        int p = bid - 2337;                  // 0..39
        const float* src; unsigned short *dhi, *dlo; int KD, CD, tI, tJ;
        if (p < 16)      { src = w1_g; dhi = wt1hi; dlo = wt1lo; KD = 128; CD = 128; tI = p >> 2; tJ = p & 3; }
        else if (p < 32) { src = w2_g; dhi = wt2hi; dlo = wt2lo; KD = 128; CD = 128; tI = (p-16) >> 2; tJ = (p-16) & 3; }
        else             { src = wo_g; dhi = wtohi; dlo = wtolo; KD = 128; CD = 64;  tI = (p-32) >> 1; tJ = (p-32) & 1; }
        int k0 = tI * 32, c0 = tJ * 32;
        #pragma unroll
        for (int it = 0; it < 4; ++it) {
            int r = (t >> 5) + it * 8;
            int c = t & 31;
            tls[r][c] = src[(size_t)(k0 + r) * CD + c0 + c];
        }
        __syncthreads();
        #pragma unroll
        for (int it = 0; it < 4; ++it) {
            int c = (t >> 5) + it * 8;
            int k = t & 31;
            unsigned short hs, ls;
            splitbf(tls[k][c], hs, ls);
            dhi[(size_t)(c0 + c) * KD + k0 + k] = hs;
            dlo[(size_t)(c0 + c) * KD + k0 + k] = ls;
        }
    }
}

// ================= Kernel 2: op attention, 8-row tiles, 1024 blocks =========
__global__ __launch_bounds__(256) void k2_opatt(
    const unsigned long long* __restrict__ rowdir,
    const unsigned short* __restrict__ trm,
    const unsigned short* __restrict__ hthi,
    const float* __restrict__ ha1, const float* __restrict__ ha2,
    const int* __restrict__ rmask, float* __restrict__ h_prime)
{
    __shared__ __align__(16) unsigned short Pl[8 * 1024];    // 16 KB
    __shared__ float ha1s[1024];
    __shared__ unsigned long long dirw[8][16];               // 1 KB
    __shared__ unsigned short trw[1024];                     // 2 KB
    __shared__ float rdeninv[8];
    int bid = blockIdx.x;
    int b = bid >> 7;
    int i0 = (bid & 127) << 3;
    int t = threadIdx.x;

    if (t < 128) {
        int rr = t >> 4, ww = t & 15;
        dirw[rr][ww] = rowdir[((size_t)(b * NN + i0 + rr)) * 16 + ww];
    }
    {
        const unsigned* src = (const unsigned*)(trm + ((size_t)(b * 64 + (i0 >> 4))) * 1024);
        ((unsigned*)trw)[t] = src[t];
        ((unsigned*)trw)[t + 256] = src[t + 256];
    }
    ha1s[t] = ha1[b * NN + t];
    ha1s[t + 256] = ha1[b * NN + t + 256];
    ha1s[t + 512] = ha1[b * NN + t + 512];
    ha1s[t + 768] = ha1[b * NN + t + 768];
    __syncthreads();

    int shbase = i0 & 8;        // row offset inside the 16-row trm window

    // ---- phase 1 (monotone-max): 8 rows x 32 lanes ----
    {
        int row = t >> 5, q = t & 31;
        int bn = b * NN + i0 + row;
        float ha2i = ha2[bn];
        unsigned rmf = rmask[bn] ? 1u : 0u;

        float mh = -INFINITY;
        #pragma unroll 8
        for (int jj = 0; jj < 32; ++jj) {
            int j = q + (jj << 5);
            unsigned bit = ((unsigned)(dirw[row][jj >> 1] >> (q + ((jj & 1) << 5))) & 1u)
                         | ((unsigned)(trw[j] >> (shbase + row)) & 1u) | rmf;
            if (bit) mh = fmaxf(mh, ha1s[j]);
        }
        #pragma unroll
        for (int m = 1; m < 32; m <<= 1) mh = fmaxf(mh, __shfl_xor(mh, m));
        float mx = ha2i + mh;
        mx = mx > 0.f ? mx : 0.01f * mx;

        float s = 0.f;
        #pragma unroll 4
        for (int jj = 0; jj < 32; ++jj) {
            int j = q + (jj << 5);
            float ev = ha2i + ha1s[j];
            ev = ev > 0.f ? ev : 0.01f * ev;
            unsigned bit = ((unsigned)(dirw[row][jj >> 1] >> (q + ((jj & 1) << 5))) & 1u)
                         | ((unsigned)(trw[j] >> (shbase + row)) & 1u) | rmf;
            float u = bit ? __expf(ev - mx) : 0.f;
            s += u;
            unsigned short pb = tobf(u);
            unsigned byteoff = ((unsigned)(row * 2048 + j * 2)) ^ ((unsigned)(row << 4));
            *(unsigned short*)((char*)Pl + byteoff) = pb;
        }
        #pragma unroll
        for (int m = 1; m < 32; m <<= 1) s += __shfl_xor(s, m);
        if (q == 0) rdeninv[row] = 1.f / s;
    }
    __syncthreads();

    // ---- phase 2: C = P @ h_hi (rows 0..7 valid) ----
    {
        int lane = t & 63, wvv = t >> 6;
        int arow = lane & 15, kg = lane >> 4;
        int prow = arow & 7;
        int col = wvv * 16 + arow;
        const unsigned short* bhp = hthi + ((size_t)(b * 64 + col)) * 1024;
        f32x4 acc = {0.f, 0.f, 0.f, 0.f};
        #pragma unroll 8
        for (int kst = 0; kst < 32; ++kst) {
            unsigned cc = ((unsigned)(kst * 4 + kg)) ^ ((unsigned)prow);
            bf16x8 pa = *(const bf16x8*)((char*)Pl + prow * 2048 + cc * 16);
            bf16x8 vh = *(const bf16x8*)&bhp[kst * 32 + kg * 8];
            acc = __builtin_amdgcn_mfma_f32_16x16x32_bf16(pa, vh, acc, 0, 0, 0);
        }
        if (kg < 2) {
            size_t base = (size_t)(b * NN + i0);
            #pragma unroll
            for (int r = 0; r < 4; ++r) {
                int orow = kg * 4 + r;          // 0..7
                float v = acc[r] * rdeninv[orow];
                h_prime[(base + orow) * 128 + col] = v;
            }
        }
    }
}

// ================= Kernel 3: ma attention, wave-per-n, 2048 blocks ==========
__global__ __launch_bounds__(256) void k3_maatt(
    const float* __restrict__ z, const unsigned long long* __restrict__ opmb,
    const float* __restrict__ h,
    const unsigned short* __restrict__ hmathi,
    const float* __restrict__ ham1, const float* __restrict__ hmaam2,
    const int* __restrict__ rmask, const float* __restrict__ wam3,
    const float* __restrict__ w_edge, float* __restrict__ h_prime)
{
    __shared__ __align__(16) unsigned short U_lds[4 * 136];
    __shared__ float wedge_s[1024];
    __shared__ float wam3s[16];
    __shared__ float zsum_s[4][16];
    __shared__ float rdeninv[4];

    int bid = blockIdx.x;
    int b = bid >> 8;
    int n0 = (bid & 255) * 4;
    int t = threadIdx.x;
    int lane = t & 63;
    int wv = t >> 6;

    for (int k = t; k < 1024; k += 256) wedge_s[k] = w_edge[k];
    if (t < 16) wam3s[t] = wam3[t];
    __syncthreads();

    {
        int bn = b * NN + n0 + wv;
        const float4* zr = (const float4*)(z + (size_t)bn * MM * 16);
        float4 a0 = zr[lane * 4 + 0];
        float4 a1 = zr[lane * 4 + 1];
        float4 a2 = zr[lane * 4 + 2];
        float4 a3 = zr[lane * 4 + 3];
        float4 c0 = zr[(lane + 64) * 4 + 0];
        float4 c1 = zr[(lane + 64) * 4 + 1];
        float4 c2 = zr[(lane + 64) * 4 + 2];
        float4 c3 = zr[(lane + 64) * 4 + 3];

        float hm0 = hmaam2[b * MM + lane];
        float hm1 = hmaam2[b * MM + 64 + lane];
        float base = ham1[bn];
        float e0 = base + hm0;
        float e1 = base + hm1;
        e0 += a0.x*wam3s[0] + a0.y*wam3s[1] + a0.z*wam3s[2] + a0.w*wam3s[3]
            + a1.x*wam3s[4] + a1.y*wam3s[5] + a1.z*wam3s[6] + a1.w*wam3s[7]
            + a2.x*wam3s[8] + a2.y*wam3s[9] + a2.z*wam3s[10] + a2.w*wam3s[11]
            + a3.x*wam3s[12] + a3.y*wam3s[13] + a3.z*wam3s[14] + a3.w*wam3s[15];
        e1 += c0.x*wam3s[0] + c0.y*wam3s[1] + c0.z*wam3s[2] + c0.w*wam3s[3]
            + c1.x*wam3s[4] + c1.y*wam3s[5] + c1.z*wam3s[6] + c1.w*wam3s[7]
            + c2.x*wam3s[8] + c2.y*wam3s[9] + c2.z*wam3s[10] + c2.w*wam3s[11]
            + c3.x*wam3s[12] + c3.y*wam3s[13] + c3.z*wam3s[14] + c3.w*wam3s[15];
        e0 = e0 > 0.f ? e0 : 0.01f * e0;
        e1 = e1 > 0.f ? e1 : 0.01f * e1;
        unsigned long long bits0 = opmb[(size_t)bn * 2];
        unsigned long long bits1 = opmb[(size_t)bn * 2 + 1];
        int rm = rmask[bn];
        int v0 = rm | (int)((bits0 >> lane) & 1ULL);
        int v1 = rm | (int)((bits1 >> lane) & 1ULL);
        e0 = v0 ? e0 : -INFINITY;
        e1 = v1 ? e1 : -INFINITY;

        float mx = fmaxf(e0, e1);
        #pragma unroll
        for (int msk = 32; msk; msk >>= 1) mx = fmaxf(mx, __shfl_xor(mx, msk));
        float u0 = __expf(e0 - mx);
        float u1 = __expf(e1 - mx);
        float s = u0 + u1;
        #pragma unroll
        for (int msk = 32; msk; msk >>= 1) s += __shfl_xor(s, msk);

        U_lds[wv * 136 + lane] = tobf(u0);
        U_lds[wv * 136 + 64 + lane] = tobf(u1);
        if (lane == 0) rdeninv[wv] = 1.f / s;

        float zv[16];
        zv[0]=u0*a0.x+u1*c0.x;  zv[1]=u0*a0.y+u1*c0.y;
        zv[2]=u0*a0.z+u1*c0.z;  zv[3]=u0*a0.w+u1*c0.w;
        zv[4]=u0*a1.x+u1*c1.x;  zv[5]=u0*a1.y+u1*c1.y;
        zv[6]=u0*a1.z+u1*c1.z;  zv[7]=u0*a1.w+u1*c1.w;
        zv[8]=u0*a2.x+u1*c2.x;  zv[9]=u0*a2.y+u1*c2.y;
        zv[10]=u0*a2.z+u1*c2.z; zv[11]=u0*a2.w+u1*c2.w;
        zv[12]=u0*a3.x+u1*c3.x; zv[13]=u0*a3.y+u1*c3.y;
        zv[14]=u0*a3.z+u1*c3.z; zv[15]=u0*a3.w+u1*c3.w;
        #pragma unroll
        for (int s2 = 0; s2 < 8; ++s2) {
            float sel = (lane & 1) ? zv[s2] : zv[s2 + 8];
            float got = __shfl_xor(sel, 1);
            zv[s2] = ((lane & 1) ? zv[s2 + 8] : zv[s2]) + got;
        }
        #pragma unroll
        for (int s2 = 0; s2 < 4; ++s2) {
            float sel = (lane & 2) ? zv[s2] : zv[s2 + 4];
            float got = __shfl_xor(sel, 2);
            zv[s2] = ((lane & 2) ? zv[s2 + 4] : zv[s2]) + got;
        }
        #pragma unroll
        for (int s2 = 0; s2 < 2; ++s2) {
            float sel = (lane & 4) ? zv[s2] : zv[s2 + 2];
            float got = __shfl_xor(sel, 4);
            zv[s2] = ((lane & 4) ? zv[s2 + 2] : zv[s2]) + got;
        }
        {
            float sel = (lane & 8) ? zv[0] : zv[1];
            float got = __shfl_xor(sel, 8);
            zv[0] = ((lane & 8) ? zv[1] : zv[0]) + got;
        }
        zv[0] += __shfl_xor(zv[0], 16);
        zv[0] += __shfl_xor(zv[0], 32);
        if (lane < 16) {
            int comp = ((lane & 1) << 3) | ((lane & 2) << 1) | ((lane & 4) >> 1) | ((lane & 8) >> 3);
            zsum_s[wv][comp] = zv[0];
        }
    }
    __syncthreads();

    {
        int arow = lane & 15, kg = lane >> 4;
        int col = wv * 16 + arow;
        bf16x8 ua[4];
        #pragma unroll
        for (int ks = 0; ks < 4; ++ks)
            ua[ks] = *(const bf16x8*)&U_lds[(arow & 3) * 136 + kg * 8 + ks * 32];
        const unsigned short* bhp = hmathi + ((size_t)(b * 64 + col)) * 128 + kg * 8;
        f32x4 acc = {0.f, 0.f, 0.f, 0.f};
        #pragma unroll
        for (int ks = 0; ks < 4; ++ks) {
            bf16x8 bh = *(const bf16x8*)&bhp[ks * 32];
            acc = __builtin_amdgcn_mfma_f32_16x16x32_bf16(ua[ks], bh, acc, 0, 0, 0);
        }
        if (kg == 0) {
            #pragma unroll
            for (int r = 0; r < 4; ++r) {
                float he = 0.f;
                #pragma unroll
                for (int i = 0; i < 16; ++i) he += zsum_s[r][i] * wedge_s[i * 64 + col];
                int bn = b * NN + n0 + r;
                float val = (acc[r] + he) * rdeninv[r] + h[(size_t)bn * 64 + col];
                h_prime[(size_t)bn * 128 + 64 + col] = val;
            }
        }
    }
}

// ================= Kernel 4: MLP via MFMA, LDS-staged weights ===============
__global__ __launch_bounds__(256) void k4_mlp(
    const float* __restrict__ hp, const int* __restrict__ rmask,
    const unsigned short* __restrict__ wt1hi, const unsigned short* __restrict__ wt1lo,
    const unsigned short* __restrict__ wt2hi, const unsigned short* __restrict__ wt2lo,
    const unsigned short* __restrict__ wtohi, const unsigned short* __restrict__ wtolo,
    const float* __restrict__ b1, const float* __restrict__ b2,
    const float* __restrict__ bo, float* __restrict__ out)
{
    __shared__ __align__(16) unsigned short Ahi0[16 * 136];
    __shared__ __align__(16) unsigned short Alo0[16 * 136];
    __shared__ __align__(16) unsigned short Ahi1[16 * 136];
    __shared__ __align__(16) unsigned short Alo1[16 * 136];
    __shared__ __align__(16) unsigned short Whi[64 * 128];   // 16 KB
    __shared__ __align__(16) unsigned short Wlo[64 * 128];   // 16 KB
    __shared__ int rml[16];
    int t = threadIdx.x;
    int lane = t & 63;
    int wv = t >> 6;
    int row0 = blockIdx.x * 16;
    int plane = t >> 7;
    int q = t & 127;

    {
        int r = t >> 4;
        int cg = (t & 15) * 8;
        const float* src = hp + (size_t)(row0 + r) * 128 + cg;
        float4 v0 = *(const float4*)src;
        float4 v1 = *(const float4*)(src + 4);
        float xs[8] = {v0.x, v0.y, v0.z, v0.w, v1.x, v1.y, v1.z, v1.w};
        u16x8 hv, lv;
        #pragma unroll
        for (int j = 0; j < 8; ++j) {
            unsigned short hs, ls;
            splitbf(xs[j], hs, ls);
            hv[j] = hs; lv[j] = ls;
        }
        *(u16x8*)&Ahi0[r * 136 + cg] = hv;
        *(u16x8*)&Alo0[r * 136 + cg] = lv;
        if (t < 16) rml[t] = rmask[row0 + t];
    }
    __syncthreads();

    int arow = lane & 15;
    int kg = lane >> 4;
    int aoff = arow * 136 + kg * 8;
    int lcol = wv * 16 + arow;          // local weight column in LDS

    // ---- layer 1: A0 -> A1 ----
    {
        bf16x8 ah[4], al[4];
        #pragma unroll
        for (int ks = 0; ks < 4; ++ks) {
            ah[ks] = *(const bf16x8*)&Ahi0[aoff + ks * 32];
            al[ks] = *(const bf16x8*)&Alo0[aoff + ks * 32];
        }
        #pragma unroll
        for (int half = 0; half < 2; ++half) {
            __syncthreads();
            {
                const unsigned short* gsrc = plane ? wt1lo : wt1hi;
                char* dst = (char*)(plane ? Wlo : Whi);
                #pragma unroll
                for (int i = 0; i < 8; ++i) {
                    int L = q * 8 + i;
                    int col = L >> 4, kc = L & 15;
                    u16x8 v = *(const u16x8*)&gsrc[(size_t)(half * 64 + col) * 128 + kc * 8];
                    unsigned byteoff = ((unsigned)(col * 256 + kc * 16)) ^ ((unsigned)((col & 7) << 4));
                    *(u16x8*)(dst + byteoff) = v;
                }
            }
            __syncthreads();
            int col = half * 64 + lcol;
            f32x4 acc = {0.f, 0.f, 0.f, 0.f};
            #pragma unroll
            for (int ks = 0; ks < 4; ++ks) {
                unsigned wb = ((unsigned)(lcol * 256 + kg * 16 + ks * 64)) ^ ((unsigned)((arow & 7) << 4));
                bf16x8 bh = *(const bf16x8*)((char*)Whi + wb);
                bf16x8 bl = *(const bf16x8*)((char*)Wlo + wb);
                acc = __builtin_amdgcn_mfma_f32_16x16x32_bf16(ah[ks], bh, acc, 0, 0, 0);
                acc = __builtin_amdgcn_mfma_f32_16x16x32_bf16(al[ks], bh, acc, 0, 0, 0);
                acc = __builtin_amdgcn_mfma_f32_16x16x32_bf16(ah[ks], bl, acc, 0, 0, 0);
            }
            float bb = b1[col];
            #pragma unroll
            for (int r = 0; r < 4; ++r) {
                int row = kg * 4 + r;
                float v = acc[r] + bb;
                v = v > 0.f ? v : __expf(v) - 1.f;
                unsigned short hs, ls;
                splitbf(v, hs, ls);
                Ahi1[row * 136 + col] = hs;
                Alo1[row * 136 + col] = ls;
            }
        }
    }
    __syncthreads();

    // ---- layer 2: A1 -> A0 ----
    {
        bf16x8 ah[4], al[4];
        #pragma unroll
        for (int ks = 0; ks < 4; ++ks) {
            ah[ks] = *(const bf16x8*)&Ahi1[aoff + ks * 32];
            al[ks] = *(const bf16x8*)&Alo1[aoff + ks * 32];
        }
        #pragma unroll
        for (int half = 0; half < 2; ++half) {
            __syncthreads();
            {
                const unsigned short* gsrc = plane ? wt2lo : wt2hi;
                char* dst = (char*)(plane ? Wlo : Whi);
                #pragma unroll
                for (int i = 0; i < 8; ++i) {
                    int L = q * 8 + i;
                    int col = L >> 4, kc = L & 15;
                    u16x8 v = *(const u16x8*)&gsrc[(size_t)(half * 64 + col) * 128 + kc * 8];
                    unsigned byteoff = ((unsigned)(col * 256 + kc * 16)) ^ ((unsigned)((col & 7) << 4));
                    *(u16x8*)(dst + byteoff) = v;
                }
            }
            __syncthreads();
            int col = half * 64 + lcol;
            f32x4 acc = {0.f, 0.f, 0.f, 0.f};
            #pragma unroll
            for (int ks = 0; ks < 4; ++ks) {
                unsigned wb = ((unsigned)(lcol * 256 + kg * 16 + ks * 64)) ^ ((unsigned)((arow & 7) << 4));
                bf16x8 bh = *(const bf16x8*)((char*)Whi + wb);
                bf16x8 bl = *(const bf16x8*)((char*)Wlo + wb);
                acc = __builtin_amdgcn_mfma_f32_16x16x32_bf16(ah[ks], bh, acc, 0, 0, 0);
                acc = __builtin_amdgcn_mfma_f32_16x16x32_bf16(al[ks], bh, acc, 0, 0, 0);
                acc = __builtin_amdgcn_mfma_f32_16x16x32_bf16(ah[ks], bl, acc, 0, 0, 0);
            }
            float bb = b2[col];
            #pragma unroll
            for (int r = 0; r < 4; ++r) {
                int row = kg * 4 + r;
                float v = acc[r] + bb;
                v = v > 0.f ? v : __expf(v) - 1.f;
                unsigned short hs, ls;
                splitbf(v, hs, ls);
                Ahi0[row * 136 + col] = hs;
                Alo0[row * 136 + col] = ls;
            }
        }
    }
    __syncthreads();

    // ---- layer 3 (output): A0 @ WO, + bo, rmask zero, store ----
    {
        bf16x8 ah[4], al[4];
        #pragma unroll
        for (int ks = 0; ks < 4; ++ks) {
            ah[ks] = *(const bf16x8*)&Ahi0[aoff + ks * 32];
            al[ks] = *(const bf16x8*)&Alo0[aoff + ks * 32];
        }
        __syncthreads();
        {
            const unsigned short* gsrc = plane ? wtolo : wtohi;
            char* dst = (char*)(plane ? Wlo : Whi);
            #pragma unroll
            for (int i = 0; i < 8; ++i) {
                int L = q * 8 + i;
                int col = L >> 4, kc = L & 15;
                u16x8 v = *(const u16x8*)&gsrc[(size_t)col * 128 + kc * 8];
                unsigned byteoff = ((unsigned)(col * 256 + kc * 16)) ^ ((unsigned)((col & 7) << 4));
                *(u16x8*)(dst + byteoff) = v;
            }
        }
        __syncthreads();
        int col = lcol;
        f32x4 acc = {0.f, 0.f, 0.f, 0.f};
        #pragma unroll
        for (int ks = 0; ks < 4; ++ks) {
            unsigned wb = ((unsigned)(lcol * 256 + kg * 16 + ks * 64)) ^ ((unsigned)((arow & 7) << 4));
            bf16x8 bh = *(const bf16x8*)((char*)Whi + wb);
            bf16x8 bl = *(const bf16x8*)((char*)Wlo + wb);
            acc = __builtin_amdgcn_mfma_f32_16x16x32_bf16(ah[ks], bh, acc, 0, 0, 0);
            acc = __builtin_amdgcn_mfma_f32_16x16x32_bf16(al[ks], bh, acc, 0, 0, 0);
            acc = __builtin_amdgcn_mfma_f32_16x16x32_bf16(ah[ks], bl, acc, 0, 0, 0);
        }
        float bb = bo[col];
        #pragma unroll
        for (int r = 0; r < 4; ++r) {
            int row = kg * 4 + r;
            float v = acc[r] + bb;
            out[(size_t)(row0 + row) * 64 + col] = rml[row] ? 0.f : v;
        }
    }
}

// ============================ launch ========================================
extern "C" void kernel_launch(void* const* d_in, const int* in_sizes, int n_in,
                              void* d_out, int out_size, void* d_ws, size_t ws_size,
                              hipStream_t stream) {
    const float* x      = (const float*)d_in[0];
    const float* y      = (const float*)d_in[1];
    const float* z      = (const float*)d_in[2];
    const int*   op_adj = (const int*)d_in[3];
    const int*   ma_adj = (const int*)d_in[4];
    const int*   opma   = (const int*)d_in[5];
    const float* w_op   = (const float*)d_in[6];
    const float* w_ma   = (const float*)d_in[7];
    const float* w_edge = (const float*)d_in[8];
    const float* att_op = (const float*)d_in[9];
    const float* att_ma = (const float*)d_in[10];
    const float* w1     = (const float*)d_in[11];
    const float* b1     = (const float*)d_in[12];
    const float* w2     = (const float*)d_in[13];
    const float* b2     = (const float*)d_in[14];
    const float* wo     = (const float*)d_in[15];
    const float* bo     = (const float*)d_in[16];
    float* out = (float*)d_out;

    float* ws = (float*)d_ws;
    float* h       = ws + OFF_H;
    float* h_ma    = ws + OFF_HMA;
    float* ha1     = ws + OFF_HA1;
    float* ha2     = ws + OFF_HA2;
    float* ham1    = ws + OFF_HAM1;
    float* hmaam2  = ws + OFF_HMAAM2;
    int*   rmask   = (int*)(ws + OFF_RMASK);
    float* wam3    = ws + OFF_WAM3;
    float* h_prime = ws + OFF_HPRIME;
    unsigned long long* rowdir = (unsigned long long*)(ws + OFF_RDIR);
    unsigned long long* opmb = (unsigned long long*)(ws + OFF_OPMB);
    unsigned short* trm   = (unsigned short*)(ws + OFF_TRM);
    unsigned short* wt1hi = (unsigned short*)(ws + OFF_WT1HI);
    unsigned short* wt1lo = (unsigned short*)(ws + OFF_WT1LO);
    unsigned short* wt2hi = (unsigned short*)(ws + OFF_WT2HI);
    unsigned short* wt2lo = (unsigned short*)(ws + OFF_WT2LO);
    unsigned short* wtohi = (unsigned short*)(ws + OFF_WTOHI);
    unsigned short* wtolo = (unsigned short*)(ws + OFF_WTOLO);
    unsigned short* hthi  = (unsigned short*)(ws + OFF_HTHI);
    unsigned short* htlo  = (unsigned short*)(ws + OFF_HTLO);
    unsigned short* hmathi = (unsigned short*)(ws + OFF_HMATHI);
    unsigned short* hmatlo = (unsigned short*)(ws + OFF_HMATLO);

    k1_prep<<<256 + 32 + 1 + 2048 + 40, 256, 0, stream>>>(
        x, y, opma, op_adj, ma_adj, w_op, w_ma, w_edge, att_op, att_ma,
        w1, w2, wo,
        h, h_ma, ha1, ha2, ham1, hmaam2, rmask, wam3, rowdir, opmb, trm,
        wt1hi, wt1lo, wt2hi, wt2lo, wtohi, wtolo, hthi, htlo, hmathi, hmatlo);

    // DIAGNOSTIC: k2 launched twice (idempotent). dur_us delta vs R14 = k2 cost.
    k2_opatt<<<1024, 256, 0, stream>>>(
        rowdir, trm, hthi, ha1, ha2, rmask, h_prime);
    k2_opatt<<<1024, 256, 0, stream>>>(
        rowdir, trm, hthi, ha1, ha2, rmask, h_prime);

    k3_maatt<<<2048, 256, 0, stream>>>(
        z, opmb, h, hmathi, ham1, hmaam2, rmask, wam3, w_edge, h_prime);

    k4_mlp<<<512, 256, 0, stream>>>(
        h_prime, rmask, wt1hi, wt1lo, wt2hi, wt2lo, wtohi, wtolo,
        b1, b2, bo, out);
}

// Round 16
// 84.404 us; speedup vs baseline: 1.2877x; 1.2877x over previous
//
#include <hip/hip_runtime.h>
#include <math.h>

#define BB 8
#define NN 1024
#define MM 128
#define FOUT 64
#define HIDN 128

// ---------------- workspace layout (floats) ----------------
#define OFF_H       0                       // B*N*64 = 524288
#define OFF_HMA     524288                  // B*M*64 = 65536
#define OFF_HA1     589824                  // B*N
#define OFF_HA2     598016                  // B*N
#define OFF_HAM1    606208                  // B*N
#define OFF_HMAAM2  614400                  // B*M
#define OFF_RMASK   615424                  // B*N (ints)
#define OFF_WAM3    623616                  // 16
#define OFF_HPRIME  623632                  // B*N*128 = 1048576
#define OFF_RDIR    1672208                 // B*N*16 u64 = 262144 floats
#define OFF_OPMB    1934352                 // B*N*2 u64 = 32768 floats
#define OFF_WT1HI   1967120                 // 128*128 u16 = 8192 floats
#define OFF_WT1LO   1975312
#define OFF_WT2HI   1983504
#define OFF_WT2LO   1991696
#define OFF_WTOHI   1999888                 // 64*128 u16 = 4096 floats
#define OFF_WTOLO   2003984
#define OFF_HTHI    2008080                 // B*64*1024 u16 = 262144 floats
#define OFF_HTLO    2270224
#define OFF_HMATHI  2532368                 // B*64*128 u16 = 32768 floats
#define OFF_HMATLO  2565136
#define OFF_TRM     2597904                 // B*64*1024 u16 = 262144 floats
// total ~2,860,048 floats ~ 11.4 MB

typedef __attribute__((ext_vector_type(8))) short bf16x8;
typedef __attribute__((ext_vector_type(8))) unsigned short u16x8;
typedef __attribute__((ext_vector_type(4))) float f32x4;

__device__ __forceinline__ void splitbf(float v, unsigned short& h, unsigned short& l) {
    unsigned u = __float_as_uint(v);
    unsigned hb = (u + 0x7FFFu + ((u >> 16) & 1u)) >> 16;
    float hf = __uint_as_float(hb << 16);
    float lf = v - hf;
    unsigned ul = __float_as_uint(lf);
    unsigned lb = (ul + 0x7FFFu + ((ul >> 16) & 1u)) >> 16;
    h = (unsigned short)hb; l = (unsigned short)lb;
}

__device__ __forceinline__ unsigned short tobf(float v) {
    unsigned u = __float_as_uint(v);
    return (unsigned short)((u + 0x7FFFu + ((u >> 16) & 1u)) >> 16);
}

// ================= Kernel 1 (fused) =========================================
// [0,1024): h 8-row blocks (4 blocks/CU); [1024,1152): h_ma 8-row blocks;
// 1152: wam3; [1153,3201): adjacency row-pack; [3201,3241): weight split.
__global__ __launch_bounds__(256) void k1_prep(
    const float* __restrict__ x, const float* __restrict__ y,
    const int* __restrict__ op_ma_adj,
    const int* __restrict__ op_adj, const int* __restrict__ ma_adj,
    const float* __restrict__ w_op, const float* __restrict__ w_ma,
    const float* __restrict__ w_edge,
    const float* __restrict__ att_op, const float* __restrict__ att_ma,
    const float* __restrict__ w1_g, const float* __restrict__ w2_g,
    const float* __restrict__ wo_g,
    float* __restrict__ h, float* __restrict__ h_ma,
    float* __restrict__ ha1, float* __restrict__ ha2, float* __restrict__ ham1,
    float* __restrict__ hmaam2, int* __restrict__ rmask, float* __restrict__ wam3,
    unsigned long long* __restrict__ rowdir, unsigned long long* __restrict__ opmb,
    unsigned short* __restrict__ trm,
    unsigned short* __restrict__ wt1hi, unsigned short* __restrict__ wt1lo,
    unsigned short* __restrict__ wt2hi, unsigned short* __restrict__ wt2lo,
    unsigned short* __restrict__ wtohi, unsigned short* __restrict__ wtolo,
    unsigned short* __restrict__ hthi, unsigned short* __restrict__ htlo,
    unsigned short* __restrict__ hmathi, unsigned short* __restrict__ hmatlo)
{
    __shared__ float wlds[64 * 64];          // 16 KB multi-purpose
    __shared__ unsigned hstage[8 * 64];      // 2 KB packed hi|lo<<16
    int bid = blockIdx.x;
    int t = threadIdx.x;
    int lane = t & 63;
    int wv = t >> 6;

    if (bid < 1024) {
        // ---- h section: 8 rows per block ----
        int b = bid >> 7;
        int n0g = (bid & 127) * 8;
        for (int k = t; k < 4096; k += 256) wlds[k] = w_op[k];
        float a1c = att_op[lane], a2c = att_op[64 + lane], am1c = att_ma[lane];
        __syncthreads();
        #pragma unroll
        for (int p = 0; p < 2; ++p) {
            int row = b * NN + n0g + p * 4 + wv;
            float xv = x[(size_t)row * 64 + lane];
            float acc0 = 0.f, acc1 = 0.f, acc2 = 0.f, acc3 = 0.f;
            #pragma unroll
            for (int i = 0; i < 16; ++i) {
                acc0 += __shfl(xv, i)      * wlds[i * 64 + lane];
                acc1 += __shfl(xv, i + 16) * wlds[(i + 16) * 64 + lane];
                acc2 += __shfl(xv, i + 32) * wlds[(i + 32) * 64 + lane];
                acc3 += __shfl(xv, i + 48) * wlds[(i + 48) * 64 + lane];
            }
            float acc = (acc0 + acc1) + (acc2 + acc3);
            h[(size_t)row * 64 + lane] = acc;
            unsigned short hs, ls;
            splitbf(acc, hs, ls);
            hstage[(p * 4 + wv) * 64 + lane] = (unsigned)hs | ((unsigned)ls << 16);
            float d1 = acc * a1c, d2 = acc * a2c, d3 = acc * am1c;
            #pragma unroll
            for (int m = 32; m; m >>= 1) {
                d1 += __shfl_xor(d1, m);
                d2 += __shfl_xor(d2, m);
                d3 += __shfl_xor(d3, m);
            }
            int v0 = op_ma_adj[(size_t)row * 128 + lane];
            int v1 = op_ma_adj[(size_t)row * 128 + 64 + lane];
            unsigned long long w0 = __ballot(v0 != 0);
            unsigned long long w1 = __ballot(v1 != 0);
            if (lane == 0) {
                ha1[row] = d1; ha2[row] = d2; ham1[row] = d3;
                opmb[row * 2] = w0; opmb[row * 2 + 1] = w1;
                rmask[row] = ((w0 | w1) == 0ULL) ? 1 : 0;
            }
        }
        __syncthreads();
        if (t < 128) {
            int o = t & 63;
            int plane = t >> 6;
            int sh = plane * 16;
            unsigned short* dst = plane ? htlo : hthi;
            u16x8 pk;
            #pragma unroll
            for (int k = 0; k < 8; ++k)
                pk[k] = (unsigned short)((hstage[k * 64 + o] >> sh) & 0xFFFFu);
            *(u16x8*)&dst[((size_t)(b * 64 + o)) * 1024 + n0g] = pk;
        }
    } else if (bid < 1152) {
        // ---- h_ma section: 8 rows per block ----
        int bb = (bid - 1024) >> 4;
        int m0 = ((bid - 1024) & 15) * 8;
        for (int k = t; k < 4096; k += 256) wlds[k] = w_ma[k];
        float am2c = att_ma[64 + lane];
        __syncthreads();
        #pragma unroll
        for (int p = 0; p < 2; ++p) {
            int row = bb * MM + m0 + p * 4 + wv;
            float yv = y[(size_t)row * 64 + lane];
            float acc0 = 0.f, acc1 = 0.f, acc2 = 0.f, acc3 = 0.f;
            #pragma unroll
            for (int i = 0; i < 16; ++i) {
                acc0 += __shfl(yv, i)      * wlds[i * 64 + lane];
                acc1 += __shfl(yv, i + 16) * wlds[(i + 16) * 64 + lane];
                acc2 += __shfl(yv, i + 32) * wlds[(i + 32) * 64 + lane];
                acc3 += __shfl(yv, i + 48) * wlds[(i + 48) * 64 + lane];
            }
            float acc = (acc0 + acc1) + (acc2 + acc3);
            h_ma[(size_t)row * 64 + lane] = acc;
            unsigned short hs, ls;
            splitbf(acc, hs, ls);
            hstage[(p * 4 + wv) * 64 + lane] = (unsigned)hs | ((unsigned)ls << 16);
            float d = acc * am2c;
            #pragma unroll
            for (int m = 32; m; m >>= 1) d += __shfl_xor(d, m);
            if (lane == 0) hmaam2[row] = d;
        }
        __syncthreads();
        if (t < 128) {
            int o = t & 63;
            int plane = t >> 6;
            int sh = plane * 16;
            unsigned short* dst = plane ? hmatlo : hmathi;
            u16x8 pk;
            #pragma unroll
            for (int k = 0; k < 8; ++k)
                pk[k] = (unsigned short)((hstage[k * 64 + o] >> sh) & 0xFFFFu);
            *(u16x8*)&dst[((size_t)(bb * 64 + o)) * 128 + m0] = pk;
        }
    } else if (bid == 1152) {
        if (t < 16) {
            float s = 0.f;
            for (int o = 0; o < 64; ++o) s += w_edge[t * 64 + o] * att_ma[128 + o];
            wam3[t] = s;
        }
    } else if (bid < 3201) {
        // ---- adjacency row-pack: 4 rows/block, int4 coalesced one-pass ----
        unsigned char (*nib)[4][64] = (unsigned char(*)[4][64])wlds; // 1 KB
        int p = bid - 1153;                  // 0..2047
        int b = p >> 8;
        int rg = p & 255;
        int rl = t >> 6;                     // local row 0..3
        int row = rg * 4 + rl;
        const int4* oprow = (const int4*)(op_adj + ((size_t)(b * NN + row)) * NN);
        const int4* marow = (const int4*)(ma_adj + ((size_t)(b * NN + row)) * NN);
        #pragma unroll
        for (int p2 = 0; p2 < 4; ++p2) {
            int4 vo = oprow[p2 * 64 + lane];
            int4 vm = marow[p2 * 64 + lane];
            unsigned nb = ((vo.x | vm.x) ? 1u : 0u) | ((vo.y | vm.y) ? 2u : 0u)
                        | ((vo.z | vm.z) ? 4u : 0u) | ((vo.w | vm.w) ? 8u : 0u);
            nib[rl][p2][lane] = (unsigned char)nb;
        }
        __syncthreads();
        if (t < 64) {
            int arl = t >> 4, q = t & 15;
            const unsigned* nw = (const unsigned*)&nib[arl][q >> 2][(q & 3) * 16];
            unsigned long long w = 0;
            #pragma unroll
            for (int u = 0; u < 4; ++u) {
                unsigned v = nw[u];
                w |= (unsigned long long)(v & 0xFu)         << (16 * u);
                w |= (unsigned long long)((v >> 8) & 0xFu)  << (16 * u + 4);
                w |= (unsigned long long)((v >> 16) & 0xFu) << (16 * u + 8);
                w |= (unsigned long long)((v >> 24) & 0xFu) << (16 * u + 12);
            }
            int jrow = rg * 4 + arl;
            rowdir[((size_t)(b * NN + jrow)) * 16 + q] = w;
            #pragma unroll
            for (int s = 0; s < 4; ++s) {
                trm[((size_t)(b * 64 + q * 4 + s)) * 1024 + jrow] =
                    (unsigned short)((w >> (16 * s)) & 0xFFFFu);
            }
        }
    } else {
        // ---- MLP weight transpose + bf16 hi/lo split, 32x32 tiles ----
        float (*tls)[33] = (float(*)[33])wlds;
        int p = bid - 3201;                  // 0..39
        const float* src; unsigned short *dhi, *dlo; int KD, CD, tI, tJ;
        if (p < 16)      { src = w1_g; dhi = wt1hi; dlo = wt1lo; KD = 128; CD = 128; tI = p >> 2; tJ = p & 3; }
        else if (p < 32) { src = w2_g; dhi = wt2hi; dlo = wt2lo; KD = 128; CD = 128; tI = (p-16) >> 2; tJ = (p-16) & 3; }
        else             { src = wo_g; dhi = wtohi; dlo = wtolo; KD = 128; CD = 64;  tI = (p-32) >> 1; tJ = (p-32) & 1; }
        int k0 = tI * 32, c0 = tJ * 32;
        #pragma unroll
        for (int it = 0; it < 4; ++it) {
            int r = (t >> 5) + it * 8;
            int c = t & 31;
            tls[r][c] = src[(size_t)(k0 + r) * CD + c0 + c];
        }
        __syncthreads();
        #pragma unroll
        for (int it = 0; it < 4; ++it) {
            int c = (t >> 5) + it * 8;
            int k = t & 31;
            unsigned short hs, ls;
            splitbf(tls[k][c], hs, ls);
            dhi[(size_t)(c0 + c) * KD + k0 + k] = hs;
            dlo[(size_t)(c0 + c) * KD + k0 + k] = ls;
        }
    }
}

// ================= Kernel 2: op attention, 8-row tiles, 1024 blocks =========
__global__ __launch_bounds__(256) void k2_opatt(
    const unsigned long long* __restrict__ rowdir,
    const unsigned short* __restrict__ trm,
    const unsigned short* __restrict__ hthi,
    const float* __restrict__ ha1, const float* __restrict__ ha2,
    const int* __restrict__ rmask, float* __restrict__ h_prime)
{
    __shared__ __align__(16) unsigned short Pl[8 * 1024];    // 16 KB
    __shared__ float ha1s[1024];
    __shared__ unsigned long long dirw[8][16];               // 1 KB
    __shared__ unsigned short trw[1024];                     // 2 KB
    __shared__ float rdeninv[8];
    int bid = blockIdx.x;
    int b = bid >> 7;
    int i0 = (bid & 127) << 3;
    int t = threadIdx.x;

    if (t < 128) {
        int rr = t >> 4, ww = t & 15;
        dirw[rr][ww] = rowdir[((size_t)(b * NN + i0 + rr)) * 16 + ww];
    }
    {
        const unsigned* src = (const unsigned*)(trm + ((size_t)(b * 64 + (i0 >> 4))) * 1024);
        ((unsigned*)trw)[t] = src[t];
        ((unsigned*)trw)[t + 256] = src[t + 256];
    }
    ha1s[t] = ha1[b * NN + t];
    ha1s[t + 256] = ha1[b * NN + t + 256];
    ha1s[t + 512] = ha1[b * NN + t + 512];
    ha1s[t + 768] = ha1[b * NN + t + 768];
    __syncthreads();

    int shbase = i0 & 8;        // row offset inside the 16-row trm window

    // ---- phase 1 (monotone-max): 8 rows x 32 lanes ----
    {
        int row = t >> 5, q = t & 31;
        int bn = b * NN + i0 + row;
        float ha2i = ha2[bn];
        unsigned rmf = rmask[bn] ? 1u : 0u;

        float mh = -INFINITY;
        #pragma unroll 8
        for (int jj = 0; jj < 32; ++jj) {
            int j = q + (jj << 5);
            unsigned bit = ((unsigned)(dirw[row][jj >> 1] >> (q + ((jj & 1) << 5))) & 1u)
                         | ((unsigned)(trw[j] >> (shbase + row)) & 1u) | rmf;
            if (bit) mh = fmaxf(mh, ha1s[j]);
        }
        #pragma unroll
        for (int m = 1; m < 32; m <<= 1) mh = fmaxf(mh, __shfl_xor(mh, m));
        float mx = ha2i + mh;
        mx = mx > 0.f ? mx : 0.01f * mx;

        float s = 0.f;
        #pragma unroll 4
        for (int jj = 0; jj < 32; ++jj) {
            int j = q + (jj << 5);
            float ev = ha2i + ha1s[j];
            ev = ev > 0.f ? ev : 0.01f * ev;
            unsigned bit = ((unsigned)(dirw[row][jj >> 1] >> (q + ((jj & 1) << 5))) & 1u)
                         | ((unsigned)(trw[j] >> (shbase + row)) & 1u) | rmf;
            float u = bit ? __expf(ev - mx) : 0.f;
            s += u;
            unsigned short pb = tobf(u);
            unsigned byteoff = ((unsigned)(row * 2048 + j * 2)) ^ ((unsigned)(row << 4));
            *(unsigned short*)((char*)Pl + byteoff) = pb;
        }
        #pragma unroll
        for (int m = 1; m < 32; m <<= 1) s += __shfl_xor(s, m);
        if (q == 0) rdeninv[row] = 1.f / s;
    }
    __syncthreads();

    // ---- phase 2: C = P @ h_hi (rows 0..7 valid) ----
    {
        int lane = t & 63, wvv = t >> 6;
        int arow = lane & 15, kg = lane >> 4;
        int prow = arow & 7;
        int col = wvv * 16 + arow;
        const unsigned short* bhp = hthi + ((size_t)(b * 64 + col)) * 1024;
        f32x4 acc = {0.f, 0.f, 0.f, 0.f};
        #pragma unroll 8
        for (int kst = 0; kst < 32; ++kst) {
            unsigned cc = ((unsigned)(kst * 4 + kg)) ^ ((unsigned)prow);
            bf16x8 pa = *(const bf16x8*)((char*)Pl + prow * 2048 + cc * 16);
            bf16x8 vh = *(const bf16x8*)&bhp[kst * 32 + kg * 8];
            acc = __builtin_amdgcn_mfma_f32_16x16x32_bf16(pa, vh, acc, 0, 0, 0);
        }
        if (kg < 2) {
            size_t base = (size_t)(b * NN + i0);
            #pragma unroll
            for (int r = 0; r < 4; ++r) {
                int orow = kg * 4 + r;          // 0..7
                float v = acc[r] * rdeninv[orow];
                h_prime[(base + orow) * 128 + col] = v;
            }
        }
    }
}

// ================= Kernel 3: ma attention, wave-per-n, 2048 blocks ==========
__global__ __launch_bounds__(256) void k3_maatt(
    const float* __restrict__ z, const unsigned long long* __restrict__ opmb,
    const float* __restrict__ h,
    const unsigned short* __restrict__ hmathi,
    const float* __restrict__ ham1, const float* __restrict__ hmaam2,
    const int* __restrict__ rmask, const float* __restrict__ wam3,
    const float* __restrict__ w_edge, float* __restrict__ h_prime)
{
    __shared__ __align__(16) unsigned short U_lds[4 * 136];
    __shared__ float wedge_s[1024];
    __shared__ float wam3s[16];
    __shared__ float zsum_s[4][16];
    __shared__ float rdeninv[4];

    int bid = blockIdx.x;
    int b = bid >> 8;
    int n0 = (bid & 255) * 4;
    int t = threadIdx.x;
    int lane = t & 63;
    int wv = t >> 6;

    for (int k = t; k < 1024; k += 256) wedge_s[k] = w_edge[k];
    if (t < 16) wam3s[t] = wam3[t];
    __syncthreads();

    {
        int bn = b * NN + n0 + wv;
        const float4* zr = (const float4*)(z + (size_t)bn * MM * 16);
        float4 a0 = zr[lane * 4 + 0];
        float4 a1 = zr[lane * 4 + 1];
        float4 a2 = zr[lane * 4 + 2];
        float4 a3 = zr[lane * 4 + 3];
        float4 c0 = zr[(lane + 64) * 4 + 0];
        float4 c1 = zr[(lane + 64) * 4 + 1];
        float4 c2 = zr[(lane + 64) * 4 + 2];
        float4 c3 = zr[(lane + 64) * 4 + 3];

        float hm0 = hmaam2[b * MM + lane];
        float hm1 = hmaam2[b * MM + 64 + lane];
        float base = ham1[bn];
        float e0 = base + hm0;
        float e1 = base + hm1;
        e0 += a0.x*wam3s[0] + a0.y*wam3s[1] + a0.z*wam3s[2] + a0.w*wam3s[3]
            + a1.x*wam3s[4] + a1.y*wam3s[5] + a1.z*wam3s[6] + a1.w*wam3s[7]
            + a2.x*wam3s[8] + a2.y*wam3s[9] + a2.z*wam3s[10] + a2.w*wam3s[11]
            + a3.x*wam3s[12] + a3.y*wam3s[13] + a3.z*wam3s[14] + a3.w*wam3s[15];
        e1 += c0.x*wam3s[0] + c0.y*wam3s[1] + c0.z*wam3s[2] + c0.w*wam3s[3]
            + c1.x*wam3s[4] + c1.y*wam3s[5] + c1.z*wam3s[6] + c1.w*wam3s[7]
            + c2.x*wam3s[8] + c2.y*wam3s[9] + c2.z*wam3s[10] + c2.w*wam3s[11]
            + c3.x*wam3s[12] + c3.y*wam3s[13] + c3.z*wam3s[14] + c3.w*wam3s[15];
        e0 = e0 > 0.f ? e0 : 0.01f * e0;
        e1 = e1 > 0.f ? e1 : 0.01f * e1;
        unsigned long long bits0 = opmb[(size_t)bn * 2];
        unsigned long long bits1 = opmb[(size_t)bn * 2 + 1];
        int rm = rmask[bn];
        int v0 = rm | (int)((bits0 >> lane) & 1ULL);
        int v1 = rm | (int)((bits1 >> lane) & 1ULL);
        e0 = v0 ? e0 : -INFINITY;
        e1 = v1 ? e1 : -INFINITY;

        float mx = fmaxf(e0, e1);
        #pragma unroll
        for (int msk = 32; msk; msk >>= 1) mx = fmaxf(mx, __shfl_xor(mx, msk));
        float u0 = __expf(e0 - mx);
        float u1 = __expf(e1 - mx);
        float s = u0 + u1;
        #pragma unroll
        for (int msk = 32; msk; msk >>= 1) s += __shfl_xor(s, msk);

        U_lds[wv * 136 + lane] = tobf(u0);
        U_lds[wv * 136 + 64 + lane] = tobf(u1);
        if (lane == 0) rdeninv[wv] = 1.f / s;

        float zv[16];
        zv[0]=u0*a0.x+u1*c0.x;  zv[1]=u0*a0.y+u1*c0.y;
        zv[2]=u0*a0.z+u1*c0.z;  zv[3]=u0*a0.w+u1*c0.w;
        zv[4]=u0*a1.x+u1*c1.x;  zv[5]=u0*a1.y+u1*c1.y;
        zv[6]=u0*a1.z+u1*c1.z;  zv[7]=u0*a1.w+u1*c1.w;
        zv[8]=u0*a2.x+u1*c2.x;  zv[9]=u0*a2.y+u1*c2.y;
        zv[10]=u0*a2.z+u1*c2.z; zv[11]=u0*a2.w+u1*c2.w;
        zv[12]=u0*a3.x+u1*c3.x; zv[13]=u0*a3.y+u1*c3.y;
        zv[14]=u0*a3.z+u1*c3.z; zv[15]=u0*a3.w+u1*c3.w;
        #pragma unroll
        for (int s2 = 0; s2 < 8; ++s2) {
            float sel = (lane & 1) ? zv[s2] : zv[s2 + 8];
            float got = __shfl_xor(sel, 1);
            zv[s2] = ((lane & 1) ? zv[s2 + 8] : zv[s2]) + got;
        }
        #pragma unroll
        for (int s2 = 0; s2 < 4; ++s2) {
            float sel = (lane & 2) ? zv[s2] : zv[s2 + 4];
            float got = __shfl_xor(sel, 2);
            zv[s2] = ((lane & 2) ? zv[s2 + 4] : zv[s2]) + got;
        }
        #pragma unroll
        for (int s2 = 0; s2 < 2; ++s2) {
            float sel = (lane & 4) ? zv[s2] : zv[s2 + 2];
            float got = __shfl_xor(sel, 4);
            zv[s2] = ((lane & 4) ? zv[s2 + 2] : zv[s2]) + got;
        }
        {
            float sel = (lane & 8) ? zv[0] : zv[1];
            float got = __shfl_xor(sel, 8);
            zv[0] = ((lane & 8) ? zv[1] : zv[0]) + got;
        }
        zv[0] += __shfl_xor(zv[0], 16);
        zv[0] += __shfl_xor(zv[0], 32);
        if (lane < 16) {
            int comp = ((lane & 1) << 3) | ((lane & 2) << 1) | ((lane & 4) >> 1) | ((lane & 8) >> 3);
            zsum_s[wv][comp] = zv[0];
        }
    }
    __syncthreads();

    {
        int arow = lane & 15, kg = lane >> 4;
        int col = wv * 16 + arow;
        bf16x8 ua[4];
        #pragma unroll
        for (int ks = 0; ks < 4; ++ks)
            ua[ks] = *(const bf16x8*)&U_lds[(arow & 3) * 136 + kg * 8 + ks * 32];
        const unsigned short* bhp = hmathi + ((size_t)(b * 64 + col)) * 128 + kg * 8;
        f32x4 acc = {0.f, 0.f, 0.f, 0.f};
        #pragma unroll
        for (int ks = 0; ks < 4; ++ks) {
            bf16x8 bh = *(const bf16x8*)&bhp[ks * 32];
            acc = __builtin_amdgcn_mfma_f32_16x16x32_bf16(ua[ks], bh, acc, 0, 0, 0);
        }
        if (kg == 0) {
            #pragma unroll
            for (int r = 0; r < 4; ++r) {
                float he = 0.f;
                #pragma unroll
                for (int i = 0; i < 16; ++i) he += zsum_s[r][i] * wedge_s[i * 64 + col];
                int bn = b * NN + n0 + r;
                float val = (acc[r] + he) * rdeninv[r] + h[(size_t)bn * 64 + col];
                h_prime[(size_t)bn * 128 + 64 + col] = val;
            }
        }
    }
}

// ================= Kernel 4: MLP via MFMA, LDS-staged weights ===============
__global__ __launch_bounds__(256) void k4_mlp(
    const float* __restrict__ hp, const int* __restrict__ rmask,
    const unsigned short* __restrict__ wt1hi, const unsigned short* __restrict__ wt1lo,
    const unsigned short* __restrict__ wt2hi, const unsigned short* __restrict__ wt2lo,
    const unsigned short* __restrict__ wtohi, const unsigned short* __restrict__ wtolo,
    const float* __restrict__ b1, const float* __restrict__ b2,
    const float* __restrict__ bo, float* __restrict__ out)
{
    __shared__ __align__(16) unsigned short Ahi0[16 * 136];
    __shared__ __align__(16) unsigned short Alo0[16 * 136];
    __shared__ __align__(16) unsigned short Ahi1[16 * 136];
    __shared__ __align__(16) unsigned short Alo1[16 * 136];
    __shared__ __align__(16) unsigned short Whi[64 * 128];   // 16 KB
    __shared__ __align__(16) unsigned short Wlo[64 * 128];   // 16 KB
    __shared__ int rml[16];
    int t = threadIdx.x;
    int lane = t & 63;
    int wv = t >> 6;
    int row0 = blockIdx.x * 16;
    int plane = t >> 7;
    int q = t & 127;

    {
        int r = t >> 4;
        int cg = (t & 15) * 8;
        const float* src = hp + (size_t)(row0 + r) * 128 + cg;
        float4 v0 = *(const float4*)src;
        float4 v1 = *(const float4*)(src + 4);
        float xs[8] = {v0.x, v0.y, v0.z, v0.w, v1.x, v1.y, v1.z, v1.w};
        u16x8 hv, lv;
        #pragma unroll
        for (int j = 0; j < 8; ++j) {
            unsigned short hs, ls;
            splitbf(xs[j], hs, ls);
            hv[j] = hs; lv[j] = ls;
        }
        *(u16x8*)&Ahi0[r * 136 + cg] = hv;
        *(u16x8*)&Alo0[r * 136 + cg] = lv;
        if (t < 16) rml[t] = rmask[row0 + t];
    }
    __syncthreads();

    int arow = lane & 15;
    int kg = lane >> 4;
    int aoff = arow * 136 + kg * 8;
    int lcol = wv * 16 + arow;          // local weight column in LDS

    // ---- layer 1: A0 -> A1 ----
    {
        bf16x8 ah[4], al[4];
        #pragma unroll
        for (int ks = 0; ks < 4; ++ks) {
            ah[ks] = *(const bf16x8*)&Ahi0[aoff + ks * 32];
            al[ks] = *(const bf16x8*)&Alo0[aoff + ks * 32];
        }
        #pragma unroll
        for (int half = 0; half < 2; ++half) {
            __syncthreads();
            {
                const unsigned short* gsrc = plane ? wt1lo : wt1hi;
                char* dst = (char*)(plane ? Wlo : Whi);
                #pragma unroll
                for (int i = 0; i < 8; ++i) {
                    int L = q * 8 + i;
                    int col = L >> 4, kc = L & 15;
                    u16x8 v = *(const u16x8*)&gsrc[(size_t)(half * 64 + col) * 128 + kc * 8];
                    unsigned byteoff = ((unsigned)(col * 256 + kc * 16)) ^ ((unsigned)((col & 7) << 4));
                    *(u16x8*)(dst + byteoff) = v;
                }
            }
            __syncthreads();
            int col = half * 64 + lcol;
            f32x4 acc = {0.f, 0.f, 0.f, 0.f};
            #pragma unroll
            for (int ks = 0; ks < 4; ++ks) {
                unsigned wb = ((unsigned)(lcol * 256 + kg * 16 + ks * 64)) ^ ((unsigned)((arow & 7) << 4));
                bf16x8 bh = *(const bf16x8*)((char*)Whi + wb);
                bf16x8 bl = *(const bf16x8*)((char*)Wlo + wb);
                acc = __builtin_amdgcn_mfma_f32_16x16x32_bf16(ah[ks], bh, acc, 0, 0, 0);
                acc = __builtin_amdgcn_mfma_f32_16x16x32_bf16(al[ks], bh, acc, 0, 0, 0);
                acc = __builtin_amdgcn_mfma_f32_16x16x32_bf16(ah[ks], bl, acc, 0, 0, 0);
            }
            float bb = b1[col];
            #pragma unroll
            for (int r = 0; r < 4; ++r) {
                int row = kg * 4 + r;
                float v = acc[r] + bb;
                v = v > 0.f ? v : __expf(v) - 1.f;
                unsigned short hs, ls;
                splitbf(v, hs, ls);
                Ahi1[row * 136 + col] = hs;
                Alo1[row * 136 + col] = ls;
            }
        }
    }
    __syncthreads();

    // ---- layer 2: A1 -> A0 ----
    {
        bf16x8 ah[4], al[4];
        #pragma unroll
        for (int ks = 0; ks < 4; ++ks) {
            ah[ks] = *(const bf16x8*)&Ahi1[aoff + ks * 32];
            al[ks] = *(const bf16x8*)&Alo1[aoff + ks * 32];
        }
        #pragma unroll
        for (int half = 0; half < 2; ++half) {
            __syncthreads();
            {
                const unsigned short* gsrc = plane ? wt2lo : wt2hi;
                char* dst = (char*)(plane ? Wlo : Whi);
                #pragma unroll
                for (int i = 0; i < 8; ++i) {
                    int L = q * 8 + i;
                    int col = L >> 4, kc = L & 15;
                    u16x8 v = *(const u16x8*)&gsrc[(size_t)(half * 64 + col) * 128 + kc * 8];
                    unsigned byteoff = ((unsigned)(col * 256 + kc * 16)) ^ ((unsigned)((col & 7) << 4));
                    *(u16x8*)(dst + byteoff) = v;
                }
            }
            __syncthreads();
            int col = half * 64 + lcol;
            f32x4 acc = {0.f, 0.f, 0.f, 0.f};
            #pragma unroll
            for (int ks = 0; ks < 4; ++ks) {
                unsigned wb = ((unsigned)(lcol * 256 + kg * 16 + ks * 64)) ^ ((unsigned)((arow & 7) << 4));
                bf16x8 bh = *(const bf16x8*)((char*)Whi + wb);
                bf16x8 bl = *(const bf16x8*)((char*)Wlo + wb);
                acc = __builtin_amdgcn_mfma_f32_16x16x32_bf16(ah[ks], bh, acc, 0, 0, 0);
                acc = __builtin_amdgcn_mfma_f32_16x16x32_bf16(al[ks], bh, acc, 0, 0, 0);
                acc = __builtin_amdgcn_mfma_f32_16x16x32_bf16(ah[ks], bl, acc, 0, 0, 0);
            }
            float bb = b2[col];
            #pragma unroll
            for (int r = 0; r < 4; ++r) {
                int row = kg * 4 + r;
                float v = acc[r] + bb;
                v = v > 0.f ? v : __expf(v) - 1.f;
                unsigned short hs, ls;
                splitbf(v, hs, ls);
                Ahi0[row * 136 + col] = hs;
                Alo0[row * 136 + col] = ls;
            }
        }
    }
    __syncthreads();

    // ---- layer 3 (output): A0 @ WO, + bo, rmask zero, store ----
    {
        bf16x8 ah[4], al[4];
        #pragma unroll
        for (int ks = 0; ks < 4; ++ks) {
            ah[ks] = *(const bf16x8*)&Ahi0[aoff + ks * 32];
            al[ks] = *(const bf16x8*)&Alo0[aoff + ks * 32];
        }
        __syncthreads();
        {
            const unsigned short* gsrc = plane ? wtolo : wtohi;
            char* dst = (char*)(plane ? Wlo : Whi);
            #pragma unroll
            for (int i = 0; i < 8; ++i) {
                int L = q * 8 + i;
                int col = L >> 4, kc = L & 15;
                u16x8 v = *(const u16x8*)&gsrc[(size_t)col * 128 + kc * 8];
                unsigned byteoff = ((unsigned)(col * 256 + kc * 16)) ^ ((unsigned)((col & 7) << 4));
                *(u16x8*)(dst + byteoff) = v;
            }
        }
        __syncthreads();
        int col = lcol;
        f32x4 acc = {0.f, 0.f, 0.f, 0.f};
        #pragma unroll
        for (int ks = 0; ks < 4; ++ks) {
            unsigned wb = ((unsigned)(lcol * 256 + kg * 16 + ks * 64)) ^ ((unsigned)((arow & 7) << 4));
            bf16x8 bh = *(const bf16x8*)((char*)Whi + wb);
            bf16x8 bl = *(const bf16x8*)((char*)Wlo + wb);
            acc = __builtin_amdgcn_mfma_f32_16x16x32_bf16(ah[ks], bh, acc, 0, 0, 0);
            acc = __builtin_amdgcn_mfma_f32_16x16x32_bf16(al[ks], bh, acc, 0, 0, 0);
            acc = __builtin_amdgcn_mfma_f32_16x16x32_bf16(ah[ks], bl, acc, 0, 0, 0);
        }
        float bb = bo[col];
        #pragma unroll
        for (int r = 0; r < 4; ++r) {
            int row = kg * 4 + r;
            float v = acc[r] + bb;
            out[(size_t)(row0 + row) * 64 + col] = rml[row] ? 0.f : v;
        }
    }
}

// ============================ launch ========================================
extern "C" void kernel_launch(void* const* d_in, const int* in_sizes, int n_in,
                              void* d_out, int out_size, void* d_ws, size_t ws_size,
                              hipStream_t stream) {
    const float* x      = (const float*)d_in[0];
    const float* y      = (const float*)d_in[1];
    const float* z      = (const float*)d_in[2];
    const int*   op_adj = (const int*)d_in[3];
    const int*   ma_adj = (const int*)d_in[4];
    const int*   opma   = (const int*)d_in[5];
    const float* w_op   = (const float*)d_in[6];
    const float* w_ma   = (const float*)d_in[7];
    const float* w_edge = (const float*)d_in[8];
    const float* att_op = (const float*)d_in[9];
    const float* att_ma = (const float*)d_in[10];
    const float* w1     = (const float*)d_in[11];
    const float* b1     = (const float*)d_in[12];
    const float* w2     = (const float*)d_in[13];
    const float* b2     = (const float*)d_in[14];
    const float* wo     = (const float*)d_in[15];
    const float* bo     = (const float*)d_in[16];
    float* out = (float*)d_out;

    float* ws = (float*)d_ws;
    float* h       = ws + OFF_H;
    float* h_ma    = ws + OFF_HMA;
    float* ha1     = ws + OFF_HA1;
    float* ha2     = ws + OFF_HA2;
    float* ham1    = ws + OFF_HAM1;
    float* hmaam2  = ws + OFF_HMAAM2;
    int*   rmask   = (int*)(ws + OFF_RMASK);
    float* wam3    = ws + OFF_WAM3;
    float* h_prime = ws + OFF_HPRIME;
    unsigned long long* rowdir = (unsigned long long*)(ws + OFF_RDIR);
    unsigned long long* opmb = (unsigned long long*)(ws + OFF_OPMB);
    unsigned short* trm   = (unsigned short*)(ws + OFF_TRM);
    unsigned short* wt1hi = (unsigned short*)(ws + OFF_WT1HI);
    unsigned short* wt1lo = (unsigned short*)(ws + OFF_WT1LO);
    unsigned short* wt2hi = (unsigned short*)(ws + OFF_WT2HI);
    unsigned short* wt2lo = (unsigned short*)(ws + OFF_WT2LO);
    unsigned short* wtohi = (unsigned short*)(ws + OFF_WTOHI);
    unsigned short* wtolo = (unsigned short*)(ws + OFF_WTOLO);
    unsigned short* hthi  = (unsigned short*)(ws + OFF_HTHI);
    unsigned short* htlo  = (unsigned short*)(ws + OFF_HTLO);
    unsigned short* hmathi = (unsigned short*)(ws + OFF_HMATHI);
    unsigned short* hmatlo = (unsigned short*)(ws + OFF_HMATLO);

    k1_prep<<<1024 + 128 + 1 + 2048 + 40, 256, 0, stream>>>(
        x, y, opma, op_adj, ma_adj, w_op, w_ma, w_edge, att_op, att_ma,
        w1, w2, wo,
        h, h_ma, ha1, ha2, ham1, hmaam2, rmask, wam3, rowdir, opmb, trm,
        wt1hi, wt1lo, wt2hi, wt2lo, wtohi, wtolo, hthi, htlo, hmathi, hmatlo);

    k2_opatt<<<1024, 256, 0, stream>>>(
        rowdir, trm, hthi, ha1, ha2, rmask, h_prime);

    k3_maatt<<<2048, 256, 0, stream>>>(
        z, opmb, h, hmathi, ham1, hmaam2, rmask, wam3, w_edge, h_prime);

    k4_mlp<<<512, 256, 0, stream>>>(
        h_prime, rmask, wt1hi, wt1lo, wt2hi, wt2lo, wtohi, wtolo,
        b1, b2, bo, out);
}

// Round 17
// 78.483 us; speedup vs baseline: 1.3848x; 1.0754x over previous
//
#include <hip/hip_runtime.h>
#include <math.h>

#define BB 8
#define NN 1024
#define MM 128
#define FOUT 64
#define HIDN 128

// ---------------- workspace layout (floats) ----------------
#define OFF_H       0                       // B*N*64 = 524288
#define OFF_HMA     524288                  // B*M*64 = 65536
#define OFF_HA1     589824                  // B*N
#define OFF_HA2     598016                  // B*N
#define OFF_HAM1    606208                  // B*N
#define OFF_HMAAM2  614400                  // B*M
#define OFF_RMASK   615424                  // B*N (ints)
#define OFF_WAM3    623616                  // 16
#define OFF_HPRIME  623632                  // B*N*128 = 1048576
#define OFF_RDIR    1672208                 // B*N*16 u64 = 262144 floats
#define OFF_OPMB    1934352                 // B*N*2 u64 = 32768 floats
#define OFF_WT1HI   1967120                 // 128*128 u16 = 8192 floats
#define OFF_WT1LO   1975312
#define OFF_WT2HI   1983504
#define OFF_WT2LO   1991696
#define OFF_WTOHI   1999888                 // 64*128 u16 = 4096 floats
#define OFF_WTOLO   2003984
#define OFF_HTHI    2008080                 // B*64*1024 u16 = 262144 floats
#define OFF_HTLO    2270224
#define OFF_HMATHI  2532368                 // B*64*128 u16 = 32768 floats
#define OFF_HMATLO  2565136
#define OFF_TRM     2597904                 // B*64*1024 u16 = 262144 floats
// total ~2,860,048 floats ~ 11.4 MB

typedef __attribute__((ext_vector_type(8))) short bf16x8;
typedef __attribute__((ext_vector_type(8))) unsigned short u16x8;
typedef __attribute__((ext_vector_type(4))) float f32x4;

__device__ __forceinline__ void splitbf(float v, unsigned short& h, unsigned short& l) {
    unsigned u = __float_as_uint(v);
    unsigned hb = (u + 0x7FFFu + ((u >> 16) & 1u)) >> 16;
    float hf = __uint_as_float(hb << 16);
    float lf = v - hf;
    unsigned ul = __float_as_uint(lf);
    unsigned lb = (ul + 0x7FFFu + ((ul >> 16) & 1u)) >> 16;
    h = (unsigned short)hb; l = (unsigned short)lb;
}

__device__ __forceinline__ unsigned short tobf(float v) {
    unsigned u = __float_as_uint(v);
    return (unsigned short)((u + 0x7FFFu + ((u >> 16) & 1u)) >> 16);
}

// ================= Kernel 1 (fused) =========================================
__global__ __launch_bounds__(256) void k1_prep(
    const float* __restrict__ x, const float* __restrict__ y,
    const int* __restrict__ op_ma_adj,
    const int* __restrict__ op_adj, const int* __restrict__ ma_adj,
    const float* __restrict__ w_op, const float* __restrict__ w_ma,
    const float* __restrict__ w_edge,
    const float* __restrict__ att_op, const float* __restrict__ att_ma,
    const float* __restrict__ w1_g, const float* __restrict__ w2_g,
    const float* __restrict__ wo_g,
    float* __restrict__ h, float* __restrict__ h_ma,
    float* __restrict__ ha1, float* __restrict__ ha2, float* __restrict__ ham1,
    float* __restrict__ hmaam2, int* __restrict__ rmask, float* __restrict__ wam3,
    unsigned long long* __restrict__ rowdir, unsigned long long* __restrict__ opmb,
    unsigned short* __restrict__ trm,
    unsigned short* __restrict__ wt1hi, unsigned short* __restrict__ wt1lo,
    unsigned short* __restrict__ wt2hi, unsigned short* __restrict__ wt2lo,
    unsigned short* __restrict__ wtohi, unsigned short* __restrict__ wtolo,
    unsigned short* __restrict__ hthi, unsigned short* __restrict__ htlo,
    unsigned short* __restrict__ hmathi, unsigned short* __restrict__ hmatlo)
{
    __shared__ float wlds[64 * 64];          // 16 KB multi-purpose
    __shared__ unsigned hstage[8 * 64];      // 2 KB packed hi|lo<<16
    int bid = blockIdx.x;
    int t = threadIdx.x;
    int lane = t & 63;
    int wv = t >> 6;

    if (bid < 1024) {
        // ---- h section: 8 rows per block ----
        int b = bid >> 7;
        int n0g = (bid & 127) * 8;
        for (int k = t; k < 4096; k += 256) wlds[k] = w_op[k];
        float a1c = att_op[lane], a2c = att_op[64 + lane], am1c = att_ma[lane];
        __syncthreads();
        #pragma unroll
        for (int p = 0; p < 2; ++p) {
            int row = b * NN + n0g + p * 4 + wv;
            float xv = x[(size_t)row * 64 + lane];
            float acc0 = 0.f, acc1 = 0.f, acc2 = 0.f, acc3 = 0.f;
            #pragma unroll
            for (int i = 0; i < 16; ++i) {
                acc0 += __shfl(xv, i)      * wlds[i * 64 + lane];
                acc1 += __shfl(xv, i + 16) * wlds[(i + 16) * 64 + lane];
                acc2 += __shfl(xv, i + 32) * wlds[(i + 32) * 64 + lane];
                acc3 += __shfl(xv, i + 48) * wlds[(i + 48) * 64 + lane];
            }
            float acc = (acc0 + acc1) + (acc2 + acc3);
            h[(size_t)row * 64 + lane] = acc;
            unsigned short hs, ls;
            splitbf(acc, hs, ls);
            hstage[(p * 4 + wv) * 64 + lane] = (unsigned)hs | ((unsigned)ls << 16);
            float d1 = acc * a1c, d2 = acc * a2c, d3 = acc * am1c;
            #pragma unroll
            for (int m = 32; m; m >>= 1) {
                d1 += __shfl_xor(d1, m);
                d2 += __shfl_xor(d2, m);
                d3 += __shfl_xor(d3, m);
            }
            int v0 = op_ma_adj[(size_t)row * 128 + lane];
            int v1 = op_ma_adj[(size_t)row * 128 + 64 + lane];
            unsigned long long w0 = __ballot(v0 != 0);
            unsigned long long w1 = __ballot(v1 != 0);
            if (lane == 0) {
                ha1[row] = d1; ha2[row] = d2; ham1[row] = d3;
                opmb[row * 2] = w0; opmb[row * 2 + 1] = w1;
                rmask[row] = ((w0 | w1) == 0ULL) ? 1 : 0;
            }
        }
        __syncthreads();
        if (t < 128) {
            int o = t & 63;
            int plane = t >> 6;
            int sh = plane * 16;
            unsigned short* dst = plane ? htlo : hthi;
            u16x8 pk;
            #pragma unroll
            for (int k = 0; k < 8; ++k)
                pk[k] = (unsigned short)((hstage[k * 64 + o] >> sh) & 0xFFFFu);
            *(u16x8*)&dst[((size_t)(b * 64 + o)) * 1024 + n0g] = pk;
        }
    } else if (bid < 1152) {
        // ---- h_ma section: 8 rows per block ----
        int bb = (bid - 1024) >> 4;
        int m0 = ((bid - 1024) & 15) * 8;
        for (int k = t; k < 4096; k += 256) wlds[k] = w_ma[k];
        float am2c = att_ma[64 + lane];
        __syncthreads();
        #pragma unroll
        for (int p = 0; p < 2; ++p) {
            int row = bb * MM + m0 + p * 4 + wv;
            float yv = y[(size_t)row * 64 + lane];
            float acc0 = 0.f, acc1 = 0.f, acc2 = 0.f, acc3 = 0.f;
            #pragma unroll
            for (int i = 0; i < 16; ++i) {
                acc0 += __shfl(yv, i)      * wlds[i * 64 + lane];
                acc1 += __shfl(yv, i + 16) * wlds[(i + 16) * 64 + lane];
                acc2 += __shfl(yv, i + 32) * wlds[(i + 32) * 64 + lane];
                acc3 += __shfl(yv, i + 48) * wlds[(i + 48) * 64 + lane];
            }
            float acc = (acc0 + acc1) + (acc2 + acc3);
            h_ma[(size_t)row * 64 + lane] = acc;
            unsigned short hs, ls;
            splitbf(acc, hs, ls);
            hstage[(p * 4 + wv) * 64 + lane] = (unsigned)hs | ((unsigned)ls << 16);
            float d = acc * am2c;
            #pragma unroll
            for (int m = 32; m; m >>= 1) d += __shfl_xor(d, m);
            if (lane == 0) hmaam2[row] = d;
        }
        __syncthreads();
        if (t < 128) {
            int o = t & 63;
            int plane = t >> 6;
            int sh = plane * 16;
            unsigned short* dst = plane ? hmatlo : hmathi;
            u16x8 pk;
            #pragma unroll
            for (int k = 0; k < 8; ++k)
                pk[k] = (unsigned short)((hstage[k * 64 + o] >> sh) & 0xFFFFu);
            *(u16x8*)&dst[((size_t)(bb * 64 + o)) * 128 + m0] = pk;
        }
    } else if (bid == 1152) {
        if (t < 16) {
            float s = 0.f;
            for (int o = 0; o < 64; ++o) s += w_edge[t * 64 + o] * att_ma[128 + o];
            wam3[t] = s;
        }
    } else if (bid < 3201) {
        // ---- adjacency row-pack: 4 rows/block, int4 coalesced one-pass ----
        unsigned char (*nib)[4][64] = (unsigned char(*)[4][64])wlds; // 1 KB
        int p = bid - 1153;                  // 0..2047
        int b = p >> 8;
        int rg = p & 255;
        int rl = t >> 6;                     // local row 0..3
        int row = rg * 4 + rl;
        const int4* oprow = (const int4*)(op_adj + ((size_t)(b * NN + row)) * NN);
        const int4* marow = (const int4*)(ma_adj + ((size_t)(b * NN + row)) * NN);
        #pragma unroll
        for (int p2 = 0; p2 < 4; ++p2) {
            int4 vo = oprow[p2 * 64 + lane];
            int4 vm = marow[p2 * 64 + lane];
            unsigned nb = ((vo.x | vm.x) ? 1u : 0u) | ((vo.y | vm.y) ? 2u : 0u)
                        | ((vo.z | vm.z) ? 4u : 0u) | ((vo.w | vm.w) ? 8u : 0u);
            nib[rl][p2][lane] = (unsigned char)nb;
        }
        __syncthreads();
        if (t < 64) {
            int arl = t >> 4, q = t & 15;
            const unsigned* nw = (const unsigned*)&nib[arl][q >> 2][(q & 3) * 16];
            unsigned long long w = 0;
            #pragma unroll
            for (int u = 0; u < 4; ++u) {
                unsigned v = nw[u];
                w |= (unsigned long long)(v & 0xFu)         << (16 * u);
                w |= (unsigned long long)((v >> 8) & 0xFu)  << (16 * u + 4);
                w |= (unsigned long long)((v >> 16) & 0xFu) << (16 * u + 8);
                w |= (unsigned long long)((v >> 24) & 0xFu) << (16 * u + 12);
            }
            int jrow = rg * 4 + arl;
            rowdir[((size_t)(b * NN + jrow)) * 16 + q] = w;
            #pragma unroll
            for (int s = 0; s < 4; ++s) {
                trm[((size_t)(b * 64 + q * 4 + s)) * 1024 + jrow] =
                    (unsigned short)((w >> (16 * s)) & 0xFFFFu);
            }
        }
    } else {
        // ---- MLP weight transpose + bf16 hi/lo split, 32x32 tiles ----
        float (*tls)[33] = (float(*)[33])wlds;
        int p = bid - 3201;                  // 0..39
        const float* src; unsigned short *dhi, *dlo; int KD, CD, tI, tJ;
        if (p < 16)      { src = w1_g; dhi = wt1hi; dlo = wt1lo; KD = 128; CD = 128; tI = p >> 2; tJ = p & 3; }
        else if (p < 32) { src = w2_g; dhi = wt2hi; dlo = wt2lo; KD = 128; CD = 128; tI = (p-16) >> 2; tJ = (p-16) & 3; }
        else             { src = wo_g; dhi = wtohi; dlo = wtolo; KD = 128; CD = 64;  tI = (p-32) >> 1; tJ = (p-32) & 1; }
        int k0 = tI * 32, c0 = tJ * 32;
        #pragma unroll
        for (int it = 0; it < 4; ++it) {
            int r = (t >> 5) + it * 8;
            int c = t & 31;
            tls[r][c] = src[(size_t)(k0 + r) * CD + c0 + c];
        }
        __syncthreads();
        #pragma unroll
        for (int it = 0; it < 4; ++it) {
            int c = (t >> 5) + it * 8;
            int k = t & 31;
            unsigned short hs, ls;
            splitbf(tls[k][c], hs, ls);
            dhi[(size_t)(c0 + c) * KD + k0 + k] = hs;
            dlo[(size_t)(c0 + c) * KD + k0 + k] = ls;
        }
    }
}

// ======= Kernel 23 (fused): op attention [0,1024) || ma attention [1024,3072)
// k2 half: global-unmasked-max softmax shift (no masked max pass).
__global__ __launch_bounds__(256) void k23_att(
    const unsigned long long* __restrict__ rowdir,
    const unsigned short* __restrict__ trm,
    const unsigned short* __restrict__ hthi,
    const float* __restrict__ ha1, const float* __restrict__ ha2,
    const float* __restrict__ z, const unsigned long long* __restrict__ opmb,
    const float* __restrict__ h,
    const unsigned short* __restrict__ hmathi,
    const float* __restrict__ ham1, const float* __restrict__ hmaam2,
    const int* __restrict__ rmask, const float* __restrict__ wam3,
    const float* __restrict__ w_edge, float* __restrict__ h_prime)
{
    // ---- k2 LDS ----
    __shared__ __align__(16) unsigned short Pl[8 * 1024];    // 16 KB
    __shared__ float ha1s[1024];
    __shared__ unsigned long long dirw[8][16];               // 1 KB
    __shared__ unsigned short trw[1024];                     // 2 KB
    __shared__ float rdeninv8[8];
    __shared__ float wmx[4];
    // ---- k3 LDS ----
    __shared__ __align__(16) unsigned short U_lds[4 * 136];
    __shared__ float wedge_s[1024];
    __shared__ float wam3s[16];
    __shared__ float zsum_s[4][16];
    __shared__ float rdeninv4[4];

    int t = threadIdx.x;
    int lane = t & 63;
    int wv = t >> 6;

    if (blockIdx.x < 1024) {
        int bid = blockIdx.x;
        int b = bid >> 7;
        int i0 = (bid & 127) << 3;

        if (t < 128) {
            int rr = t >> 4, ww = t & 15;
            dirw[rr][ww] = rowdir[((size_t)(b * NN + i0 + rr)) * 16 + ww];
        }
        {
            const unsigned* src = (const unsigned*)(trm + ((size_t)(b * 64 + (i0 >> 4))) * 1024);
            ((unsigned*)trw)[t] = src[t];
            ((unsigned*)trw)[t + 256] = src[t + 256];
        }
        float v0 = ha1[b * NN + t];
        float v1 = ha1[b * NN + t + 256];
        float v2 = ha1[b * NN + t + 512];
        float v3 = ha1[b * NN + t + 768];
        ha1s[t] = v0; ha1s[t + 256] = v1; ha1s[t + 512] = v2; ha1s[t + 768] = v3;
        // block-global max of ha1 (softmax shift; any C >= masked max is valid)
        float m4 = fmaxf(fmaxf(v0, v1), fmaxf(v2, v3));
        #pragma unroll
        for (int m = 1; m < 64; m <<= 1) m4 = fmaxf(m4, __shfl_xor(m4, m));
        if (lane == 0) wmx[wv] = m4;
        __syncthreads();
        float mhall = fmaxf(fmaxf(wmx[0], wmx[1]), fmaxf(wmx[2], wmx[3]));

        int shbase = i0 & 8;

        // ---- phase 1: single pass (global-max shift) ----
        {
            int row = t >> 5, q = t & 31;
            int bn = b * NN + i0 + row;
            float ha2i = ha2[bn];
            unsigned rmf = rmask[bn] ? 1u : 0u;
            float mx = ha2i + mhall;
            mx = mx > 0.f ? mx : 0.01f * mx;

            float s = 0.f;
            #pragma unroll 4
            for (int jj = 0; jj < 32; ++jj) {
                int j = q + (jj << 5);
                float ev = ha2i + ha1s[j];
                ev = ev > 0.f ? ev : 0.01f * ev;
                unsigned bit = ((unsigned)(dirw[row][jj >> 1] >> (q + ((jj & 1) << 5))) & 1u)
                             | ((unsigned)(trw[j] >> (shbase + row)) & 1u) | rmf;
                float u = bit ? __expf(ev - mx) : 0.f;
                s += u;
                unsigned short pb = tobf(u);
                unsigned byteoff = ((unsigned)(row * 2048 + j * 2)) ^ ((unsigned)(row << 4));
                *(unsigned short*)((char*)Pl + byteoff) = pb;
            }
            #pragma unroll
            for (int m = 1; m < 32; m <<= 1) s += __shfl_xor(s, m);
            if (q == 0) rdeninv8[row] = 1.f / s;
        }
        __syncthreads();

        // ---- phase 2: C = P @ h_hi (rows 0..7 valid) ----
        {
            int arow = lane & 15, kg = lane >> 4;
            int prow = arow & 7;
            int col = wv * 16 + arow;
            const unsigned short* bhp = hthi + ((size_t)(b * 64 + col)) * 1024;
            f32x4 acc = {0.f, 0.f, 0.f, 0.f};
            #pragma unroll 8
            for (int kst = 0; kst < 32; ++kst) {
                unsigned cc = ((unsigned)(kst * 4 + kg)) ^ ((unsigned)prow);
                bf16x8 pa = *(const bf16x8*)((char*)Pl + prow * 2048 + cc * 16);
                bf16x8 vh = *(const bf16x8*)&bhp[kst * 32 + kg * 8];
                acc = __builtin_amdgcn_mfma_f32_16x16x32_bf16(pa, vh, acc, 0, 0, 0);
            }
            if (kg < 2) {
                size_t base = (size_t)(b * NN + i0);
                #pragma unroll
                for (int r = 0; r < 4; ++r) {
                    int orow = kg * 4 + r;
                    float v = acc[r] * rdeninv8[orow];
                    h_prime[(base + orow) * 128 + col] = v;
                }
            }
        }
        return;
    }

    // =================== k3 half: ma attention, wave-per-n ===================
    int bid = blockIdx.x - 1024;
    int b = bid >> 8;
    int n0 = (bid & 255) * 4;

    for (int k = t; k < 1024; k += 256) wedge_s[k] = w_edge[k];
    if (t < 16) wam3s[t] = wam3[t];
    __syncthreads();

    {
        int bn = b * NN + n0 + wv;
        const float4* zr = (const float4*)(z + (size_t)bn * MM * 16);
        float4 a0 = zr[lane * 4 + 0];
        float4 a1 = zr[lane * 4 + 1];
        float4 a2 = zr[lane * 4 + 2];
        float4 a3 = zr[lane * 4 + 3];
        float4 c0 = zr[(lane + 64) * 4 + 0];
        float4 c1 = zr[(lane + 64) * 4 + 1];
        float4 c2 = zr[(lane + 64) * 4 + 2];
        float4 c3 = zr[(lane + 64) * 4 + 3];

        float hm0 = hmaam2[b * MM + lane];
        float hm1 = hmaam2[b * MM + 64 + lane];
        float base = ham1[bn];
        float e0 = base + hm0;
        float e1 = base + hm1;
        e0 += a0.x*wam3s[0] + a0.y*wam3s[1] + a0.z*wam3s[2] + a0.w*wam3s[3]
            + a1.x*wam3s[4] + a1.y*wam3s[5] + a1.z*wam3s[6] + a1.w*wam3s[7]
            + a2.x*wam3s[8] + a2.y*wam3s[9] + a2.z*wam3s[10] + a2.w*wam3s[11]
            + a3.x*wam3s[12] + a3.y*wam3s[13] + a3.z*wam3s[14] + a3.w*wam3s[15];
        e1 += c0.x*wam3s[0] + c0.y*wam3s[1] + c0.z*wam3s[2] + c0.w*wam3s[3]
            + c1.x*wam3s[4] + c1.y*wam3s[5] + c1.z*wam3s[6] + c1.w*wam3s[7]
            + c2.x*wam3s[8] + c2.y*wam3s[9] + c2.z*wam3s[10] + c2.w*wam3s[11]
            + c3.x*wam3s[12] + c3.y*wam3s[13] + c3.z*wam3s[14] + c3.w*wam3s[15];
        e0 = e0 > 0.f ? e0 : 0.01f * e0;
        e1 = e1 > 0.f ? e1 : 0.01f * e1;
        unsigned long long bits0 = opmb[(size_t)bn * 2];
        unsigned long long bits1 = opmb[(size_t)bn * 2 + 1];
        int rm = rmask[bn];
        int v0 = rm | (int)((bits0 >> lane) & 1ULL);
        int v1 = rm | (int)((bits1 >> lane) & 1ULL);
        e0 = v0 ? e0 : -INFINITY;
        e1 = v1 ? e1 : -INFINITY;

        float mx = fmaxf(e0, e1);
        #pragma unroll
        for (int msk = 32; msk; msk >>= 1) mx = fmaxf(mx, __shfl_xor(mx, msk));
        float u0 = __expf(e0 - mx);
        float u1 = __expf(e1 - mx);
        float s = u0 + u1;
        #pragma unroll
        for (int msk = 32; msk; msk >>= 1) s += __shfl_xor(s, msk);

        U_lds[wv * 136 + lane] = tobf(u0);
        U_lds[wv * 136 + 64 + lane] = tobf(u1);
        if (lane == 0) rdeninv4[wv] = 1.f / s;

        float zv[16];
        zv[0]=u0*a0.x+u1*c0.x;  zv[1]=u0*a0.y+u1*c0.y;
        zv[2]=u0*a0.z+u1*c0.z;  zv[3]=u0*a0.w+u1*c0.w;
        zv[4]=u0*a1.x+u1*c1.x;  zv[5]=u0*a1.y+u1*c1.y;
        zv[6]=u0*a1.z+u1*c1.z;  zv[7]=u0*a1.w+u1*c1.w;
        zv[8]=u0*a2.x+u1*c2.x;  zv[9]=u0*a2.y+u1*c2.y;
        zv[10]=u0*a2.z+u1*c2.z; zv[11]=u0*a2.w+u1*c2.w;
        zv[12]=u0*a3.x+u1*c3.x; zv[13]=u0*a3.y+u1*c3.y;
        zv[14]=u0*a3.z+u1*c3.z; zv[15]=u0*a3.w+u1*c3.w;
        #pragma unroll
        for (int s2 = 0; s2 < 8; ++s2) {
            float sel = (lane & 1) ? zv[s2] : zv[s2 + 8];
            float got = __shfl_xor(sel, 1);
            zv[s2] = ((lane & 1) ? zv[s2 + 8] : zv[s2]) + got;
        }
        #pragma unroll
        for (int s2 = 0; s2 < 4; ++s2) {
            float sel = (lane & 2) ? zv[s2] : zv[s2 + 4];
            float got = __shfl_xor(sel, 2);
            zv[s2] = ((lane & 2) ? zv[s2 + 4] : zv[s2]) + got;
        }
        #pragma unroll
        for (int s2 = 0; s2 < 2; ++s2) {
            float sel = (lane & 4) ? zv[s2] : zv[s2 + 2];
            float got = __shfl_xor(sel, 4);
            zv[s2] = ((lane & 4) ? zv[s2 + 2] : zv[s2]) + got;
        }
        {
            float sel = (lane & 8) ? zv[0] : zv[1];
            float got = __shfl_xor(sel, 8);
            zv[0] = ((lane & 8) ? zv[1] : zv[0]) + got;
        }
        zv[0] += __shfl_xor(zv[0], 16);
        zv[0] += __shfl_xor(zv[0], 32);
        if (lane < 16) {
            int comp = ((lane & 1) << 3) | ((lane & 2) << 1) | ((lane & 4) >> 1) | ((lane & 8) >> 3);
            zsum_s[wv][comp] = zv[0];
        }
    }
    __syncthreads();

    {
        int arow = lane & 15, kg = lane >> 4;
        int col = wv * 16 + arow;
        bf16x8 ua[4];
        #pragma unroll
        for (int ks = 0; ks < 4; ++ks)
            ua[ks] = *(const bf16x8*)&U_lds[(arow & 3) * 136 + kg * 8 + ks * 32];
        const unsigned short* bhp = hmathi + ((size_t)(b * 64 + col)) * 128 + kg * 8;
        f32x4 acc = {0.f, 0.f, 0.f, 0.f};
        #pragma unroll
        for (int ks = 0; ks < 4; ++ks) {
            bf16x8 bh = *(const bf16x8*)&bhp[ks * 32];
            acc = __builtin_amdgcn_mfma_f32_16x16x32_bf16(ua[ks], bh, acc, 0, 0, 0);
        }
        if (kg == 0) {
            #pragma unroll
            for (int r = 0; r < 4; ++r) {
                float he = 0.f;
                #pragma unroll
                for (int i = 0; i < 16; ++i) he += zsum_s[r][i] * wedge_s[i * 64 + col];
                int bn = b * NN + n0 + r;
                float val = (acc[r] + he) * rdeninv4[r] + h[(size_t)bn * 64 + col];
                h_prime[(size_t)bn * 128 + 64 + col] = val;
            }
        }
    }
}

// ================= Kernel 4: MLP via MFMA, LDS-staged weights ===============
__global__ __launch_bounds__(256) void k4_mlp(
    const float* __restrict__ hp, const int* __restrict__ rmask,
    const unsigned short* __restrict__ wt1hi, const unsigned short* __restrict__ wt1lo,
    const unsigned short* __restrict__ wt2hi, const unsigned short* __restrict__ wt2lo,
    const unsigned short* __restrict__ wtohi, const unsigned short* __restrict__ wtolo,
    const float* __restrict__ b1, const float* __restrict__ b2,
    const float* __restrict__ bo, float* __restrict__ out)
{
    __shared__ __align__(16) unsigned short Ahi0[16 * 136];
    __shared__ __align__(16) unsigned short Alo0[16 * 136];
    __shared__ __align__(16) unsigned short Ahi1[16 * 136];
    __shared__ __align__(16) unsigned short Alo1[16 * 136];
    __shared__ __align__(16) unsigned short Whi[64 * 128];   // 16 KB
    __shared__ __align__(16) unsigned short Wlo[64 * 128];   // 16 KB
    __shared__ int rml[16];
    int t = threadIdx.x;
    int lane = t & 63;
    int wv = t >> 6;
    int row0 = blockIdx.x * 16;
    int plane = t >> 7;
    int q = t & 127;

    {
        int r = t >> 4;
        int cg = (t & 15) * 8;
        const float* src = hp + (size_t)(row0 + r) * 128 + cg;
        float4 v0 = *(const float4*)src;
        float4 v1 = *(const float4*)(src + 4);
        float xs[8] = {v0.x, v0.y, v0.z, v0.w, v1.x, v1.y, v1.z, v1.w};
        u16x8 hv, lv;
        #pragma unroll
        for (int j = 0; j < 8; ++j) {
            unsigned short hs, ls;
            splitbf(xs[j], hs, ls);
            hv[j] = hs; lv[j] = ls;
        }
        *(u16x8*)&Ahi0[r * 136 + cg] = hv;
        *(u16x8*)&Alo0[r * 136 + cg] = lv;
        if (t < 16) rml[t] = rmask[row0 + t];
    }
    __syncthreads();

    int arow = lane & 15;
    int kg = lane >> 4;
    int aoff = arow * 136 + kg * 8;
    int lcol = wv * 16 + arow;          // local weight column in LDS

    // ---- layer 1: A0 -> A1 ----
    {
        bf16x8 ah[4], al[4];
        #pragma unroll
        for (int ks = 0; ks < 4; ++ks) {
            ah[ks] = *(const bf16x8*)&Ahi0[aoff + ks * 32];
            al[ks] = *(const bf16x8*)&Alo0[aoff + ks * 32];
        }
        #pragma unroll
        for (int half = 0; half < 2; ++half) {
            __syncthreads();
            {
                const unsigned short* gsrc = plane ? wt1lo : wt1hi;
                char* dst = (char*)(plane ? Wlo : Whi);
                #pragma unroll
                for (int i = 0; i < 8; ++i) {
                    int L = q * 8 + i;
                    int col = L >> 4, kc = L & 15;
                    u16x8 v = *(const u16x8*)&gsrc[(size_t)(half * 64 + col) * 128 + kc * 8];
                    unsigned byteoff = ((unsigned)(col * 256 + kc * 16)) ^ ((unsigned)((col & 7) << 4));
                    *(u16x8*)(dst + byteoff) = v;
                }
            }
            __syncthreads();
            int col = half * 64 + lcol;
            f32x4 acc = {0.f, 0.f, 0.f, 0.f};
            #pragma unroll
            for (int ks = 0; ks < 4; ++ks) {
                unsigned wb = ((unsigned)(lcol * 256 + kg * 16 + ks * 64)) ^ ((unsigned)((arow & 7) << 4));
                bf16x8 bh = *(const bf16x8*)((char*)Whi + wb);
                bf16x8 bl = *(const bf16x8*)((char*)Wlo + wb);
                acc = __builtin_amdgcn_mfma_f32_16x16x32_bf16(ah[ks], bh, acc, 0, 0, 0);
                acc = __builtin_amdgcn_mfma_f32_16x16x32_bf16(al[ks], bh, acc, 0, 0, 0);
                acc = __builtin_amdgcn_mfma_f32_16x16x32_bf16(ah[ks], bl, acc, 0, 0, 0);
            }
            float bb = b1[col];
            #pragma unroll
            for (int r = 0; r < 4; ++r) {
                int row = kg * 4 + r;
                float v = acc[r] + bb;
                v = v > 0.f ? v : __expf(v) - 1.f;
                unsigned short hs, ls;
                splitbf(v, hs, ls);
                Ahi1[row * 136 + col] = hs;
                Alo1[row * 136 + col] = ls;
            }
        }
    }
    __syncthreads();

    // ---- layer 2: A1 -> A0 ----
    {
        bf16x8 ah[4], al[4];
        #pragma unroll
        for (int ks = 0; ks < 4; ++ks) {
            ah[ks] = *(const bf16x8*)&Ahi1[aoff + ks * 32];
            al[ks] = *(const bf16x8*)&Alo1[aoff + ks * 32];
        }
        #pragma unroll
        for (int half = 0; half < 2; ++half) {
            __syncthreads();
            {
                const unsigned short* gsrc = plane ? wt2lo : wt2hi;
                char* dst = (char*)(plane ? Wlo : Whi);
                #pragma unroll
                for (int i = 0; i < 8; ++i) {
                    int L = q * 8 + i;
                    int col = L >> 4, kc = L & 15;
                    u16x8 v = *(const u16x8*)&gsrc[(size_t)(half * 64 + col) * 128 + kc * 8];
                    unsigned byteoff = ((unsigned)(col * 256 + kc * 16)) ^ ((unsigned)((col & 7) << 4));
                    *(u16x8*)(dst + byteoff) = v;
                }
            }
            __syncthreads();
            int col = half * 64 + lcol;
            f32x4 acc = {0.f, 0.f, 0.f, 0.f};
            #pragma unroll
            for (int ks = 0; ks < 4; ++ks) {
                unsigned wb = ((unsigned)(lcol * 256 + kg * 16 + ks * 64)) ^ ((unsigned)((arow & 7) << 4));
                bf16x8 bh = *(const bf16x8*)((char*)Whi + wb);
                bf16x8 bl = *(const bf16x8*)((char*)Wlo + wb);
                acc = __builtin_amdgcn_mfma_f32_16x16x32_bf16(ah[ks], bh, acc, 0, 0, 0);
                acc = __builtin_amdgcn_mfma_f32_16x16x32_bf16(al[ks], bh, acc, 0, 0, 0);
                acc = __builtin_amdgcn_mfma_f32_16x16x32_bf16(ah[ks], bl, acc, 0, 0, 0);
            }
            float bb = b2[col];
            #pragma unroll
            for (int r = 0; r < 4; ++r) {
                int row = kg * 4 + r;
                float v = acc[r] + bb;
                v = v > 0.f ? v : __expf(v) - 1.f;
                unsigned short hs, ls;
                splitbf(v, hs, ls);
                Ahi0[row * 136 + col] = hs;
                Alo0[row * 136 + col] = ls;
            }
        }
    }
    __syncthreads();

    // ---- layer 3 (output): A0 @ WO, + bo, rmask zero, store ----
    {
        bf16x8 ah[4], al[4];
        #pragma unroll
        for (int ks = 0; ks < 4; ++ks) {
            ah[ks] = *(const bf16x8*)&Ahi0[aoff + ks * 32];
            al[ks] = *(const bf16x8*)&Alo0[aoff + ks * 32];
        }
        __syncthreads();
        {
            const unsigned short* gsrc = plane ? wtolo : wtohi;
            char* dst = (char*)(plane ? Wlo : Whi);
            #pragma unroll
            for (int i = 0; i < 8; ++i) {
                int L = q * 8 + i;
                int col = L >> 4, kc = L & 15;
                u16x8 v = *(const u16x8*)&gsrc[(size_t)col * 128 + kc * 8];
                unsigned byteoff = ((unsigned)(col * 256 + kc * 16)) ^ ((unsigned)((col & 7) << 4));
                *(u16x8*)(dst + byteoff) = v;
            }
        }
        __syncthreads();
        int col = lcol;
        f32x4 acc = {0.f, 0.f, 0.f, 0.f};
        #pragma unroll
        for (int ks = 0; ks < 4; ++ks) {
            unsigned wb = ((unsigned)(lcol * 256 + kg * 16 + ks * 64)) ^ ((unsigned)((arow & 7) << 4));
            bf16x8 bh = *(const bf16x8*)((char*)Whi + wb);
            bf16x8 bl = *(const bf16x8*)((char*)Wlo + wb);
            acc = __builtin_amdgcn_mfma_f32_16x16x32_bf16(ah[ks], bh, acc, 0, 0, 0);
            acc = __builtin_amdgcn_mfma_f32_16x16x32_bf16(al[ks], bh, acc, 0, 0, 0);
            acc = __builtin_amdgcn_mfma_f32_16x16x32_bf16(ah[ks], bl, acc, 0, 0, 0);
        }
        float bb = bo[col];
        #pragma unroll
        for (int r = 0; r < 4; ++r) {
            int row = kg * 4 + r;
            float v = acc[r] + bb;
            out[(size_t)(row0 + row) * 64 + col] = rml[row] ? 0.f : v;
        }
    }
}

// ============================ launch ========================================
extern "C" void kernel_launch(void* const* d_in, const int* in_sizes, int n_in,
                              void* d_out, int out_size, void* d_ws, size_t ws_size,
                              hipStream_t stream) {
    const float* x      = (const float*)d_in[0];
    const float* y      = (const float*)d_in[1];
    const float* z      = (const float*)d_in[2];
    const int*   op_adj = (const int*)d_in[3];
    const int*   ma_adj = (const int*)d_in[4];
    const int*   opma   = (const int*)d_in[5];
    const float* w_op   = (const float*)d_in[6];
    const float* w_ma   = (const float*)d_in[7];
    const float* w_edge = (const float*)d_in[8];
    const float* att_op = (const float*)d_in[9];
    const float* att_ma = (const float*)d_in[10];
    const float* w1     = (const float*)d_in[11];
    const float* b1     = (const float*)d_in[12];
    const float* w2     = (const float*)d_in[13];
    const float* b2     = (const float*)d_in[14];
    const float* wo     = (const float*)d_in[15];
    const float* bo     = (const float*)d_in[16];
    float* out = (float*)d_out;

    float* ws = (float*)d_ws;
    float* h       = ws + OFF_H;
    float* h_ma    = ws + OFF_HMA;
    float* ha1     = ws + OFF_HA1;
    float* ha2     = ws + OFF_HA2;
    float* ham1    = ws + OFF_HAM1;
    float* hmaam2  = ws + OFF_HMAAM2;
    int*   rmask   = (int*)(ws + OFF_RMASK);
    float* wam3    = ws + OFF_WAM3;
    float* h_prime = ws + OFF_HPRIME;
    unsigned long long* rowdir = (unsigned long long*)(ws + OFF_RDIR);
    unsigned long long* opmb = (unsigned long long*)(ws + OFF_OPMB);
    unsigned short* trm   = (unsigned short*)(ws + OFF_TRM);
    unsigned short* wt1hi = (unsigned short*)(ws + OFF_WT1HI);
    unsigned short* wt1lo = (unsigned short*)(ws + OFF_WT1LO);
    unsigned short* wt2hi = (unsigned short*)(ws + OFF_WT2HI);
    unsigned short* wt2lo = (unsigned short*)(ws + OFF_WT2LO);
    unsigned short* wtohi = (unsigned short*)(ws + OFF_WTOHI);
    unsigned short* wtolo = (unsigned short*)(ws + OFF_WTOLO);
    unsigned short* hthi  = (unsigned short*)(ws + OFF_HTHI);
    unsigned short* htlo  = (unsigned short*)(ws + OFF_HTLO);
    unsigned short* hmathi = (unsigned short*)(ws + OFF_HMATHI);
    unsigned short* hmatlo = (unsigned short*)(ws + OFF_HMATLO);

    k1_prep<<<1024 + 128 + 1 + 2048 + 40, 256, 0, stream>>>(
        x, y, opma, op_adj, ma_adj, w_op, w_ma, w_edge, att_op, att_ma,
        w1, w2, wo,
        h, h_ma, ha1, ha2, ham1, hmaam2, rmask, wam3, rowdir, opmb, trm,
        wt1hi, wt1lo, wt2hi, wt2lo, wtohi, wtolo, hthi, htlo, hmathi, hmatlo);

    k23_att<<<3072, 256, 0, stream>>>(
        rowdir, trm, hthi, ha1, ha2,
        z, opmb, h, hmathi, ham1, hmaam2, rmask, wam3, w_edge, h_prime);

    k4_mlp<<<512, 256, 0, stream>>>(
        h_prime, rmask, wt1hi, wt1lo, wt2hi, wt2lo, wtohi, wtolo,
        b1, b2, bo, out);
}